// Round 8
// baseline (122.455 us; speedup 1.0000x reference)
//
#include <hip/hip_runtime.h>
#include <math.h>

#define N 1024
#define DIM 128
#define LAMB 0.9f
#define INV2SIG2 (1.0f / 450.0f)   // 0.5 / sigma^2, sigma=15

typedef short v8s __attribute__((ext_vector_type(8)));
typedef float v4f __attribute__((ext_vector_type(4)));

__device__ __forceinline__ unsigned short f2bf(float x) {   // RNE float->bf16
    unsigned int u = __float_as_uint(x);
    u += 0x7FFFu + ((u >> 16) & 1u);
    return (unsigned short)(u >> 16);
}
__device__ __forceinline__ float bf2f(unsigned short h) {
    return __uint_as_float(((unsigned int)h) << 16);
}
__device__ __forceinline__ v8s cvt8(const float* p) {      // 8 fp32 -> v8s bf16
    v8s r;
    #pragma unroll
    for (int i = 0; i < 8; ++i) r[i] = (short)f2bf(p[i]);
    return r;
}

// Device-coherent store: visible device-wide once vmcnt retires -> barriers need
// no L2 wb/inv (validated rounds 3/5/7).
__device__ __forceinline__ void st_dc_f32(float* p, float v) {
    asm volatile("global_store_dword %0, %1, off sc0 sc1" :: "v"(p), "v"(v) : "memory");
}
__device__ __forceinline__ void st_dc_u16(unsigned short* p, unsigned short v) {
    unsigned int vv = v;
    asm volatile("global_store_short %0, %1, off sc0 sc1" :: "v"(p), "v"(vv) : "memory");
}

// Fence-free 64-block grid barrier (validated round 7).
__device__ __forceinline__ void gridbar64(unsigned int* bar, unsigned int tgt) {
    asm volatile("s_waitcnt vmcnt(0)" ::: "memory");   // dc stores drained
    __syncthreads();
    if (threadIdx.x == 0) {
        atomicAdd(bar, 1u);
        unsigned int v;
        do {
            __builtin_amdgcn_s_sleep(1);
            v = __hip_atomic_load(bar, __ATOMIC_RELAXED, __HIP_MEMORY_SCOPE_AGENT);
        } while (v < tgt);
    }
    __syncthreads();
}

// ---------------- THE kernel: compose|gemm|aff|mv x3|epilogue, 64 blocks ----------
// Block b owns output rows 16b..16b+15 in gemm/aff/mv; the 16x1024 affinity
// stripe lives in registers (abf[16][2]/lane) and NEVER touches memory.
__global__ __launch_bounds__(256) void k_all(
    const float* __restrict__ f,
    const float* __restrict__ w1, const float* __restrict__ b1,
    const float* __restrict__ w2, const float* __restrict__ b2,
    const float* __restrict__ w3, const float* __restrict__ b3,
    const float* __restrict__ w4, const float* __restrict__ b4,
    float* __restrict__ ws, float* __restrict__ out)
{
    float* Wboth = ws;                                    // 256x128 fp32
    float* bboth = ws + 32768;                            // 256
    float* fn2   = ws + 33024;                            // 1024 (plain stores now)
    float* mag   = ws + 34048;                            // 1024
    float* total0p = ws + 35072;                          // 1 float
    unsigned int* bar     = (unsigned int*)(ws + 36096);  // memset-zeroed
    unsigned int* donecnt = (unsigned int*)(ws + 36097);  // memset-zeroed
    float* A0  = ws + 36352;                              // 1024
    float* zb0 = ws + 37376;
    float* zb1 = ws + 38400;
    float* zb2 = ws + 39424;
    unsigned short* xb = (unsigned short*)(ws + 40448);   // 1024x128 bf16

    __shared__ __align__(16) float ubuf[4][2][128];   // per-wave compose chains
    __shared__ __align__(16) float zsh[1024];
    __shared__ float red[16][4];
    __shared__ float tot16[16];
    __shared__ float red4[4];
    __shared__ float bvalS;
    __shared__ __align__(16) float ush[1024];
    __shared__ int winner;

    const int b = blockIdx.x, t = threadIdx.x;
    const int wave = t >> 6, lane = t & 63;
    const int l15 = lane & 15, quad = lane >> 4;
    const int rbase = b * 16;

    // ======== phase 0: compose. 4 composed rows/block, one per wave. ========
    // G row (crow<128): W4[crow]*W3*W2 ; X row: W1[crow-128]*W4*W3*W2.
    // Per-wave private LDS chain, coalesced column reads (lane j, j+64).
    {
        const int crow = b * 4 + wave;
        const bool isG = (crow < 128);
        const int j0 = lane;
        const float* rowp = isG ? (w4 + crow * 128) : (w1 + (crow - 128) * 128);
        const float* m1   = isG ? w3 : w4;
        float a0 = 0.f, a1 = 0.f;
        #pragma unroll 16
        for (int k = 0; k < 128; ++k) {
            float u = rowp[k];
            a0 += u * m1[k * 128 + j0];
            a1 += u * m1[k * 128 + j0 + 64];
        }
        ubuf[wave][0][j0] = a0; ubuf[wave][0][j0 + 64] = a1;
        int cur = 0;
        if (!isG) {                      // extra middle hop through w3
            float c0 = 0.f, c1 = 0.f;
            #pragma unroll 16
            for (int k = 0; k < 128; ++k) {
                float u = ubuf[wave][0][k];
                c0 += u * w3[k * 128 + j0];
                c1 += u * w3[k * 128 + j0 + 64];
            }
            ubuf[wave][1][j0] = c0; ubuf[wave][1][j0 + 64] = c1;
            cur = 1;
        }
        float d0 = 0.f, d1 = 0.f;
        #pragma unroll 16
        for (int k = 0; k < 128; ++k) {
            float u = ubuf[wave][cur][k];
            d0 += u * w2[k * 128 + j0];
            d1 += u * w2[k * 128 + j0 + 64];
        }
        st_dc_f32(&Wboth[crow * 128 + j0], d0);
        st_dc_f32(&Wboth[crow * 128 + j0 + 64], d1);
    }
    if (b == 0) {                        // bias chain (3 dependent vec-mats)
        __syncthreads();
        float* bv1 = zsh; float* bv2 = zsh + 128;   // zsh free until mv phase
        if (t < 128) {
            float a = b3[t];
            #pragma unroll 8
            for (int k = 0; k < 128; ++k) a += w3[t * 128 + k] * b2[k];
            bv1[t] = a;
        }
        __syncthreads();
        if (t < 128) {
            float a = b4[t];
            #pragma unroll 8
            for (int k = 0; k < 128; ++k) a += w4[t * 128 + k] * bv1[k];
            bv2[t] = a;
            st_dc_f32(&bboth[t], a);     // bg
        }
        __syncthreads();
        if (t < 128) {
            float a = b1[t];
            #pragma unroll 8
            for (int k = 0; k < 128; ++k) a += w1[t * 128 + k] * bv2[k];
            st_dc_f32(&bboth[128 + t], a);   // bx
        }
    }
    gridbar64(bar, 64);

    // ======== phase 1: gemm. My 16 rows x 256 cols; fn2/mag block-local. ========
    {
        const float* ap = f + (rbase + l15) * 128 + quad * 8;
        v8s afr[4];
        #pragma unroll
        for (int kc = 0; kc < 4; ++kc) afr[kc] = cvt8(ap + kc * 32);
        float rp[4] = {0.f, 0.f, 0.f, 0.f};
        #pragma unroll
        for (int s = 0; s < 4; ++s) {
            const int j0 = wave * 64 + s * 16;
            const float* bp = Wboth + (j0 + l15) * 128 + quad * 8;
            v4f acc = {0.f, 0.f, 0.f, 0.f};
            #pragma unroll
            for (int kc = 0; kc < 4; ++kc)
                acc = __builtin_amdgcn_mfma_f32_16x16x32_bf16(
                          afr[kc], cvt8(bp + kc * 32), acc, 0, 0, 0);
            const float bias = bboth[j0 + l15];
            #pragma unroll
            for (int reg = 0; reg < 4; ++reg) {
                float yv = acc[reg] + bias;
                rp[reg] += yv * yv;
                if (j0 >= 128)          // X half -> xb (wave-uniform branch)
                    st_dc_u16(&xb[(rbase + quad * 4 + reg) * DIM + (j0 - 128) + l15],
                              f2bf(yv));
            }
        }
        #pragma unroll
        for (int reg = 0; reg < 4; ++reg) {
            float ss = rp[reg];
            ss += __shfl_xor(ss, 1, 64); ss += __shfl_xor(ss, 2, 64);
            ss += __shfl_xor(ss, 4, 64); ss += __shfl_xor(ss, 8, 64);
            if (l15 == 0) red[quad * 4 + reg][wave] = ss;
        }
        __syncthreads();
        if (t < 16) {                    // waves 0,1 = G cols; 2,3 = X cols
            st_dc_f32(&fn2[rbase + t], red[t][0] + red[t][1]);
            st_dc_f32(&mag[rbase + t], red[t][2] + red[t][3]);
        }
    }
    gridbar64(bar, 128);

    // ======== phase 2: affinity. My 16 rows x all 1024 cols -> registers. ========
    unsigned int abf[16][2];             // packed bf16 a: [s][regpair], fully static
    {
        const unsigned short* ap2 = xb + (rbase + l15) * DIM + quad * 8;
        v8s afr2[4];
        #pragma unroll
        for (int kc = 0; kc < 4; ++kc) afr2[kc] = *(const v8s*)(ap2 + kc * 32);
        float rowsum[4] = {0.f, 0.f, 0.f, 0.f};
        #pragma unroll
        for (int s = 0; s < 16; ++s) {
            const int j0 = wave * 256 + s * 16;
            const unsigned short* bp = xb + (j0 + l15) * DIM + quad * 8;
            v4f acc = {0.f, 0.f, 0.f, 0.f};
            #pragma unroll
            for (int kc = 0; kc < 4; ++kc)
                acc = __builtin_amdgcn_mfma_f32_16x16x32_bf16(
                          afr2[kc], *(const v8s*)(bp + kc * 32), acc, 0, 0, 0);
            const int gj = j0 + l15;
            const float rm = 1.0f / mag[gj];
            const float fj = fn2[gj] * INV2SIG2;
            float av[4];
            #pragma unroll
            for (int reg = 0; reg < 4; ++reg) {
                const int gi = rbase + quad * 4 + reg;
                float Sv = acc[reg] * rm - 1.0f;
                av[reg] = (gi == gj) ? 0.f : __expf(-(Sv * Sv) * fj);
                rowsum[reg] += av[reg];
            }
            abf[s][0] = (unsigned int)f2bf(av[0]) | ((unsigned int)f2bf(av[1]) << 16);
            abf[s][1] = (unsigned int)f2bf(av[2]) | ((unsigned int)f2bf(av[3]) << 16);
            if (b == 0 && quad == 0) st_dc_f32(&A0[gj], av[0]);   // fp32 row 0
        }
        #pragma unroll
        for (int reg = 0; reg < 4; ++reg) {
            float ss = rowsum[reg];
            ss += __shfl_xor(ss, 1, 64); ss += __shfl_xor(ss, 2, 64);
            ss += __shfl_xor(ss, 4, 64); ss += __shfl_xor(ss, 8, 64);
            if (l15 == 0) red[quad * 4 + reg][wave] = ss;
        }
        __syncthreads();
        if (t < 16) {
            float tv = red[t][0] + red[t][1] + red[t][2] + red[t][3];
            tot16[t] = tv;
            if (rbase + t == 0) st_dc_f32(total0p, tv);
        }
        __syncthreads();
    }
    gridbar64(bar, 192);

    // ======== phases 3-5: Neumann chain, affinity stripe stays in registers ======
    const float r0s = 1.0f / fmaxf(*total0p, 1e-10f);

    #pragma unroll 1
    for (int it = 0; it < 3; ++it) {
        const float* zsrc = (it == 0) ? A0 : ((it == 1) ? zb0 : zb1);
        float* zdst = (it == 0) ? zb0 : ((it == 1) ? zb1 : zb2);
        const float zsc = (it == 0) ? r0s : 1.0f;
        ((float4*)zsh)[t] = ((const float4*)zsrc)[t];   // stage z (4 KB)
        __syncthreads();
        float part[4] = {0.f, 0.f, 0.f, 0.f};
        #pragma unroll
        for (int s = 0; s < 16; ++s) {
            const float zv = zsh[wave * 256 + s * 16 + l15];
            part[0] += bf2f((unsigned short)(abf[s][0])) * zv;
            part[1] += bf2f((unsigned short)(abf[s][0] >> 16)) * zv;
            part[2] += bf2f((unsigned short)(abf[s][1])) * zv;
            part[3] += bf2f((unsigned short)(abf[s][1] >> 16)) * zv;
        }
        #pragma unroll
        for (int reg = 0; reg < 4; ++reg) {
            float ss = part[reg];
            ss += __shfl_xor(ss, 1, 64); ss += __shfl_xor(ss, 2, 64);
            ss += __shfl_xor(ss, 4, 64); ss += __shfl_xor(ss, 8, 64);
            if (l15 == 0) red[quad * 4 + reg][wave] = ss;
        }
        __syncthreads();
        if (t < 16) {
            const int r = rbase + t;
            float dot = red[t][0] + red[t][1] + red[t][2] + red[t][3];
            float rsc = (r == 0) ? 0.f : LAMB / fmaxf(tot16[t], 1e-10f);
            float p0r = (r == 0) ? 0.f : A0[r] * r0s;
            st_dc_f32(&zdst[r], p0r + rsc * zsc * dot);
        }
        if (it == 0) gridbar64(bar, 256);
        else if (it == 1) gridbar64(bar, 320);
    }

    // last-block-done: fence-free (dc stores + vmcnt drain), 64 blocks
    asm volatile("s_waitcnt vmcnt(0)" ::: "memory");
    __syncthreads();
    if (t == 0) {
        unsigned int old = atomicAdd(donecnt, 1u);
        winner = (old == 63u) ? 1 : 0;
    }
    __syncthreads();
    if (!winner) return;

    // ---- 256-thread Aitken + softmax epilogue: zM=zb2, zM1=zb1, zM2=zb0 ----
    const float* zM  = zb2;
    const float* zM1 = zb1;
    const float* zM2 = zb0;
    float av[4], d1v[4];
    float s12 = 0.f, s22 = 0.f;
    #pragma unroll
    for (int k = 0; k < 4; ++k) {
        const int e = t + 256 * k;
        av[k] = zM[e];
        float bb = zM1[e], cc = zM2[e];
        d1v[k] = av[k] - bb;
        float d2 = bb - cc;
        s12 += d1v[k] * d2;
        s22 += d2 * d2;
    }
    #pragma unroll
    for (int off = 32; off >= 1; off >>= 1) s12 += __shfl_down(s12, off, 64);
    if (lane == 0) red4[wave] = s12;
    __syncthreads();
    if (t == 0) bvalS = red4[0] + red4[1] + red4[2] + red4[3];
    __syncthreads();
    const float dot12 = bvalS;
    __syncthreads();
    #pragma unroll
    for (int off = 32; off >= 1; off >>= 1) s22 += __shfl_down(s22, off, 64);
    if (lane == 0) red4[wave] = s22;
    __syncthreads();
    if (t == 0) bvalS = red4[0] + red4[1] + red4[2] + red4[3];
    __syncthreads();
    const float dot22 = bvalS;
    __syncthreads();

    float lam = dot12 / fmaxf(dot22, 1e-30f);
    lam = fminf(fmaxf(lam, 0.0f), 0.95f);
    const float coef = lam / (1.0f - lam);
    #pragma unroll
    for (int k = 0; k < 4; ++k) ush[t + 256 * k] = av[k] + coef * d1v[k];
    __syncthreads();

    float Pv[4];
    float ps = 0.f;
    #pragma unroll
    for (int k = 0; k < 4; ++k) {
        const int e = t + 256 * k;
        Pv[k] = (e >= 1) ? 0.1f * ush[e] : 0.f;
        ps += Pv[k];
    }
    #pragma unroll
    for (int off = 32; off >= 1; off >>= 1) ps += __shfl_down(ps, off, 64);
    if (lane == 0) red4[wave] = ps;
    __syncthreads();
    if (t == 0) bvalS = (red4[0] + red4[1] + red4[2] + red4[3]) / 1023.0f;
    __syncthreads();
    const float mean = bvalS;
    __syncthreads();

    float mx = 0.f;
    #pragma unroll
    for (int k = 0; k < 4; ++k) {
        const int e = t + 256 * k;
        if (e >= 1) {
            Pv[k] = fmaxf(Pv[k] - mean, 0.f) * 100.f;
            mx = fmaxf(mx, Pv[k]);
        }
    }
    #pragma unroll
    for (int off = 32; off >= 1; off >>= 1) mx = fmaxf(mx, __shfl_down(mx, off, 64));
    if (lane == 0) red4[wave] = mx;
    __syncthreads();
    if (t == 0) bvalS = fmaxf(fmaxf(red4[0], red4[1]), fmaxf(red4[2], red4[3]));
    __syncthreads();
    const float gmax = bvalS;
    __syncthreads();

    float Ev[4];
    float es = 0.f;
    #pragma unroll
    for (int k = 0; k < 4; ++k) {
        const int e = t + 256 * k;
        Ev[k] = (e >= 1) ? expf(Pv[k] - gmax) : 0.f;
        es += Ev[k];
    }
    #pragma unroll
    for (int off = 32; off >= 1; off >>= 1) es += __shfl_down(es, off, 64);
    if (lane == 0) red4[wave] = es;
    __syncthreads();
    if (t == 0) bvalS = red4[0] + red4[1] + red4[2] + red4[3];
    __syncthreads();
    const float esum = bvalS;
    #pragma unroll
    for (int k = 0; k < 4; ++k) {
        const int e = t + 256 * k;
        if (e >= 1) out[e - 1] = Ev[k] / esum;
    }
}

extern "C" void kernel_launch(void* const* d_in, const int* in_sizes, int n_in,
                              void* d_out, int out_size, void* d_ws, size_t ws_size,
                              hipStream_t stream) {
    const float* f  = (const float*)d_in[0];
    const float* w1 = (const float*)d_in[1];
    const float* b1 = (const float*)d_in[2];
    const float* w2 = (const float*)d_in[3];
    const float* b2 = (const float*)d_in[4];
    const float* w3 = (const float*)d_in[5];
    const float* b3 = (const float*)d_in[6];
    const float* w4 = (const float*)d_in[7];
    const float* b4 = (const float*)d_in[8];
    float* ws = (float*)d_ws;

    // bar + donecnt (monotonic counters) cannot self-zero across graph replays.
    (void)hipMemsetAsync((char*)d_ws + 36096 * 4, 0, 8, stream);

    k_all<<<64, 256, 0, stream>>>(f, w1, b1, w2, b2, w3, b3, w4, b4,
                                  ws, (float*)d_out);
}

// Round 9
// 109.177 us; speedup vs baseline: 1.1216x; 1.1216x over previous
//
#include <hip/hip_runtime.h>
#include <math.h>

#define N 1024
#define DIM 128
#define LAMB 0.9f
#define INV2SIG2 (1.0f / 450.0f)   // 0.5 / sigma^2, sigma=15

typedef short v8s __attribute__((ext_vector_type(8)));
typedef float v4f __attribute__((ext_vector_type(4)));

__device__ __forceinline__ unsigned short f2bf(float x) {   // RNE float->bf16
    unsigned int u = __float_as_uint(x);
    u += 0x7FFFu + ((u >> 16) & 1u);
    return (unsigned short)(u >> 16);
}
__device__ __forceinline__ float bf2f(unsigned short h) {
    return __uint_as_float(((unsigned int)h) << 16);
}
__device__ __forceinline__ v8s cvt8(const float* p) {      // 8 fp32 -> v8s bf16
    v8s r;
    #pragma unroll
    for (int i = 0; i < 8; ++i) r[i] = (short)f2bf(p[i]);
    return r;
}

// Device-coherent store: visible device-wide once vmcnt retires (rounds 3/5/7/8).
__device__ __forceinline__ void st_dc_f32(float* p, float v) {
    asm volatile("global_store_dword %0, %1, off sc0 sc1" :: "v"(p), "v"(v) : "memory");
}
__device__ __forceinline__ void st_dc_u16(unsigned short* p, unsigned short v) {
    unsigned int vv = v;
    asm volatile("global_store_short %0, %1, off sc0 sc1" :: "v"(p), "v"(vv) : "memory");
}

// Fence-free 64-block grid barrier (validated rounds 7/8).
__device__ __forceinline__ void gridbar64(unsigned int* bar, unsigned int tgt) {
    asm volatile("s_waitcnt vmcnt(0)" ::: "memory");   // dc stores drained
    __syncthreads();
    if (threadIdx.x == 0) {
        atomicAdd(bar, 1u);
        unsigned int v;
        do {
            __builtin_amdgcn_s_sleep(1);
            v = __hip_atomic_load(bar, __ATOMIC_RELAXED, __HIP_MEMORY_SCOPE_AGENT);
        } while (v < tgt);
    }
    __syncthreads();
}

// ---------------- THE kernel: 4-layer MLP (row-local, NO compose, NO global sync)
//                  | aff-in-regs | mv x3 | epilogue.  64 blocks x 16 rows. ----------
__global__ __launch_bounds__(256) void k_all(
    const float* __restrict__ f,
    const float* __restrict__ w1, const float* __restrict__ b1,
    const float* __restrict__ w2, const float* __restrict__ b2,
    const float* __restrict__ w3, const float* __restrict__ b3,
    const float* __restrict__ w4, const float* __restrict__ b4,
    float* __restrict__ ws, float* __restrict__ out)
{
    float* fn2   = ws + 33024;                            // 1024
    float* mag   = ws + 34048;                            // 1024
    float* total0p = ws + 35072;                          // 1 float
    unsigned int* bar     = (unsigned int*)(ws + 36096);  // memset-zeroed
    unsigned int* donecnt = (unsigned int*)(ws + 36097);  // memset-zeroed
    float* A0  = ws + 36352;                              // 1024
    float* zb0 = ws + 37376;
    float* zb1 = ws + 38400;
    float* zb2 = ws + 39424;
    unsigned short* xb = (unsigned short*)(ws + 40448);   // 1024x128 bf16

    // act rows padded to 136 ushorts (272B = 17x16B: b128-aligned frag reads)
    __shared__ __align__(16) unsigned short actL[2][16][136];
    __shared__ __align__(16) float zsh[1024];
    __shared__ float red[16][4];
    __shared__ float tot16[16];
    __shared__ float red4[4];
    __shared__ float bvalS;
    __shared__ __align__(16) float ush[1024];
    __shared__ int winner;

    const int b = blockIdx.x, t = threadIdx.x;
    const int wave = t >> 6, lane = t & 63;
    const int l15 = lane & 15, quad = lane >> 4;
    const int rbase = b * 16;
    const int jw = wave * 32;            // this wave's 32-col slice per layer

    // ======== phase 0: MLP chain, entirely block-local (no grid sync) ========
    {
        // layer 1: y = f @ w2^T + b2   (A-frags straight from global f)
        const float* ap = f + (rbase + l15) * 128 + quad * 8;
        v8s a0 = cvt8(ap), a1 = cvt8(ap + 32), a2 = cvt8(ap + 64), a3 = cvt8(ap + 96);
        #pragma unroll
        for (int jj = 0; jj < 2; ++jj) {
            const int jt = jw + jj * 16;
            const float* wp = w2 + (jt + l15) * 128 + quad * 8;
            v4f acc = {0.f, 0.f, 0.f, 0.f};
            acc = __builtin_amdgcn_mfma_f32_16x16x32_bf16(a0, cvt8(wp), acc, 0, 0, 0);
            acc = __builtin_amdgcn_mfma_f32_16x16x32_bf16(a1, cvt8(wp + 32), acc, 0, 0, 0);
            acc = __builtin_amdgcn_mfma_f32_16x16x32_bf16(a2, cvt8(wp + 64), acc, 0, 0, 0);
            acc = __builtin_amdgcn_mfma_f32_16x16x32_bf16(a3, cvt8(wp + 96), acc, 0, 0, 0);
            const float bias = b2[jt + l15];
            #pragma unroll
            for (int reg = 0; reg < 4; ++reg)
                actL[0][quad * 4 + reg][jt + l15] = f2bf(acc[reg] + bias);
        }
        __syncthreads();

        // layer 2: y = @ w3^T + b3   (actL[0] -> actL[1])
        const unsigned short* lp0 = &actL[0][l15][quad * 8];
        a0 = *(const v8s*)(lp0); a1 = *(const v8s*)(lp0 + 32);
        a2 = *(const v8s*)(lp0 + 64); a3 = *(const v8s*)(lp0 + 96);
        #pragma unroll
        for (int jj = 0; jj < 2; ++jj) {
            const int jt = jw + jj * 16;
            const float* wp = w3 + (jt + l15) * 128 + quad * 8;
            v4f acc = {0.f, 0.f, 0.f, 0.f};
            acc = __builtin_amdgcn_mfma_f32_16x16x32_bf16(a0, cvt8(wp), acc, 0, 0, 0);
            acc = __builtin_amdgcn_mfma_f32_16x16x32_bf16(a1, cvt8(wp + 32), acc, 0, 0, 0);
            acc = __builtin_amdgcn_mfma_f32_16x16x32_bf16(a2, cvt8(wp + 64), acc, 0, 0, 0);
            acc = __builtin_amdgcn_mfma_f32_16x16x32_bf16(a3, cvt8(wp + 96), acc, 0, 0, 0);
            const float bias = b3[jt + l15];
            #pragma unroll
            for (int reg = 0; reg < 4; ++reg)
                actL[1][quad * 4 + reg][jt + l15] = f2bf(acc[reg] + bias);
        }
        __syncthreads();

        // layer 3: g = @ w4^T + b4   (actL[1] -> actL[0]); fn2 = |g|^2 per row
        const unsigned short* lp1 = &actL[1][l15][quad * 8];
        a0 = *(const v8s*)(lp1); a1 = *(const v8s*)(lp1 + 32);
        a2 = *(const v8s*)(lp1 + 64); a3 = *(const v8s*)(lp1 + 96);
        float rpg[4] = {0.f, 0.f, 0.f, 0.f};
        #pragma unroll
        for (int jj = 0; jj < 2; ++jj) {
            const int jt = jw + jj * 16;
            const float* wp = w4 + (jt + l15) * 128 + quad * 8;
            v4f acc = {0.f, 0.f, 0.f, 0.f};
            acc = __builtin_amdgcn_mfma_f32_16x16x32_bf16(a0, cvt8(wp), acc, 0, 0, 0);
            acc = __builtin_amdgcn_mfma_f32_16x16x32_bf16(a1, cvt8(wp + 32), acc, 0, 0, 0);
            acc = __builtin_amdgcn_mfma_f32_16x16x32_bf16(a2, cvt8(wp + 64), acc, 0, 0, 0);
            acc = __builtin_amdgcn_mfma_f32_16x16x32_bf16(a3, cvt8(wp + 96), acc, 0, 0, 0);
            const float bias = b4[jt + l15];
            #pragma unroll
            for (int reg = 0; reg < 4; ++reg) {
                float y = acc[reg] + bias;
                rpg[reg] += y * y;
                actL[0][quad * 4 + reg][jt + l15] = f2bf(y);
            }
        }
        __syncthreads();                 // actL[0] complete; red free
        #pragma unroll
        for (int reg = 0; reg < 4; ++reg) {
            float ss = rpg[reg];
            ss += __shfl_xor(ss, 1, 64); ss += __shfl_xor(ss, 2, 64);
            ss += __shfl_xor(ss, 4, 64); ss += __shfl_xor(ss, 8, 64);
            if (l15 == 0) red[quad * 4 + reg][wave] = ss;
        }
        __syncthreads();
        if (t < 16) st_dc_f32(&fn2[rbase + t],
                              red[t][0] + red[t][1] + red[t][2] + red[t][3]);

        // layer 4: x = g @ w1^T + b1   (actL[0] -> xb global); mag = |x|^2
        a0 = *(const v8s*)(lp0); a1 = *(const v8s*)(lp0 + 32);
        a2 = *(const v8s*)(lp0 + 64); a3 = *(const v8s*)(lp0 + 96);
        float rpx[4] = {0.f, 0.f, 0.f, 0.f};
        #pragma unroll
        for (int jj = 0; jj < 2; ++jj) {
            const int jt = jw + jj * 16;
            const float* wp = w1 + (jt + l15) * 128 + quad * 8;
            v4f acc = {0.f, 0.f, 0.f, 0.f};
            acc = __builtin_amdgcn_mfma_f32_16x16x32_bf16(a0, cvt8(wp), acc, 0, 0, 0);
            acc = __builtin_amdgcn_mfma_f32_16x16x32_bf16(a1, cvt8(wp + 32), acc, 0, 0, 0);
            acc = __builtin_amdgcn_mfma_f32_16x16x32_bf16(a2, cvt8(wp + 64), acc, 0, 0, 0);
            acc = __builtin_amdgcn_mfma_f32_16x16x32_bf16(a3, cvt8(wp + 96), acc, 0, 0, 0);
            const float bias = b1[jt + l15];
            #pragma unroll
            for (int reg = 0; reg < 4; ++reg) {
                float y = acc[reg] + bias;
                rpx[reg] += y * y;
                st_dc_u16(&xb[(rbase + quad * 4 + reg) * DIM + jt + l15], f2bf(y));
            }
        }
        __syncthreads();                 // red free again
        #pragma unroll
        for (int reg = 0; reg < 4; ++reg) {
            float ss = rpx[reg];
            ss += __shfl_xor(ss, 1, 64); ss += __shfl_xor(ss, 2, 64);
            ss += __shfl_xor(ss, 4, 64); ss += __shfl_xor(ss, 8, 64);
            if (l15 == 0) red[quad * 4 + reg][wave] = ss;
        }
        __syncthreads();
        if (t < 16) st_dc_f32(&mag[rbase + t],
                              red[t][0] + red[t][1] + red[t][2] + red[t][3]);
    }
    gridbar64(bar, 64);

    // ======== phase 1: affinity. My 16 rows x all 1024 cols -> registers. ========
    unsigned int abf[16][2];             // packed bf16 affinity stripe (validated r8)
    {
        const unsigned short* ap2 = xb + (rbase + l15) * DIM + quad * 8;
        v8s afr2[4];
        #pragma unroll
        for (int kc = 0; kc < 4; ++kc) afr2[kc] = *(const v8s*)(ap2 + kc * 32);
        float rowsum[4] = {0.f, 0.f, 0.f, 0.f};
        #pragma unroll
        for (int s = 0; s < 16; ++s) {
            const int j0 = wave * 256 + s * 16;
            const unsigned short* bp = xb + (j0 + l15) * DIM + quad * 8;
            v4f acc = {0.f, 0.f, 0.f, 0.f};
            #pragma unroll
            for (int kc = 0; kc < 4; ++kc)
                acc = __builtin_amdgcn_mfma_f32_16x16x32_bf16(
                          afr2[kc], *(const v8s*)(bp + kc * 32), acc, 0, 0, 0);
            const int gj = j0 + l15;
            const float rm = 1.0f / mag[gj];
            const float fj = fn2[gj] * INV2SIG2;
            float av[4];
            #pragma unroll
            for (int reg = 0; reg < 4; ++reg) {
                const int gi = rbase + quad * 4 + reg;
                float Sv = acc[reg] * rm - 1.0f;
                av[reg] = (gi == gj) ? 0.f : __expf(-(Sv * Sv) * fj);
                rowsum[reg] += av[reg];
            }
            abf[s][0] = (unsigned int)f2bf(av[0]) | ((unsigned int)f2bf(av[1]) << 16);
            abf[s][1] = (unsigned int)f2bf(av[2]) | ((unsigned int)f2bf(av[3]) << 16);
            if (b == 0 && quad == 0) st_dc_f32(&A0[gj], av[0]);   // fp32 row 0
        }
        #pragma unroll
        for (int reg = 0; reg < 4; ++reg) {
            float ss = rowsum[reg];
            ss += __shfl_xor(ss, 1, 64); ss += __shfl_xor(ss, 2, 64);
            ss += __shfl_xor(ss, 4, 64); ss += __shfl_xor(ss, 8, 64);
            if (l15 == 0) red[quad * 4 + reg][wave] = ss;
        }
        __syncthreads();
        if (t < 16) {
            float tv = red[t][0] + red[t][1] + red[t][2] + red[t][3];
            tot16[t] = tv;
            if (rbase + t == 0) st_dc_f32(total0p, tv);
        }
        __syncthreads();
    }
    gridbar64(bar, 128);

    // ======== phases 2-4: Neumann chain, affinity stripe stays in registers ======
    const float r0s = 1.0f / fmaxf(*total0p, 1e-10f);

    #pragma unroll 1
    for (int it = 0; it < 3; ++it) {
        const float* zsrc = (it == 0) ? A0 : ((it == 1) ? zb0 : zb1);
        float* zdst = (it == 0) ? zb0 : ((it == 1) ? zb1 : zb2);
        const float zsc = (it == 0) ? r0s : 1.0f;
        ((float4*)zsh)[t] = ((const float4*)zsrc)[t];   // stage z (4 KB)
        __syncthreads();
        float part[4] = {0.f, 0.f, 0.f, 0.f};
        #pragma unroll
        for (int s = 0; s < 16; ++s) {
            const float zv = zsh[wave * 256 + s * 16 + l15];
            part[0] += bf2f((unsigned short)(abf[s][0])) * zv;
            part[1] += bf2f((unsigned short)(abf[s][0] >> 16)) * zv;
            part[2] += bf2f((unsigned short)(abf[s][1])) * zv;
            part[3] += bf2f((unsigned short)(abf[s][1] >> 16)) * zv;
        }
        #pragma unroll
        for (int reg = 0; reg < 4; ++reg) {
            float ss = part[reg];
            ss += __shfl_xor(ss, 1, 64); ss += __shfl_xor(ss, 2, 64);
            ss += __shfl_xor(ss, 4, 64); ss += __shfl_xor(ss, 8, 64);
            if (l15 == 0) red[quad * 4 + reg][wave] = ss;
        }
        __syncthreads();
        if (t < 16) {
            const int r = rbase + t;
            float dot = red[t][0] + red[t][1] + red[t][2] + red[t][3];
            float rsc = (r == 0) ? 0.f : LAMB / fmaxf(tot16[t], 1e-10f);
            float p0r = (r == 0) ? 0.f : A0[r] * r0s;
            st_dc_f32(&zdst[r], p0r + rsc * zsc * dot);
        }
        if (it == 0) gridbar64(bar, 192);
        else if (it == 1) gridbar64(bar, 256);
    }

    // last-block-done: fence-free (dc stores + vmcnt drain), 64 blocks
    asm volatile("s_waitcnt vmcnt(0)" ::: "memory");
    __syncthreads();
    if (t == 0) {
        unsigned int old = atomicAdd(donecnt, 1u);
        winner = (old == 63u) ? 1 : 0;
    }
    __syncthreads();
    if (!winner) return;

    // ---- 256-thread Aitken + softmax epilogue: zM=zb2, zM1=zb1, zM2=zb0 ----
    const float* zM  = zb2;
    const float* zM1 = zb1;
    const float* zM2 = zb0;
    float av[4], d1v[4];
    float s12 = 0.f, s22 = 0.f;
    #pragma unroll
    for (int k = 0; k < 4; ++k) {
        const int e = t + 256 * k;
        av[k] = zM[e];
        float bb = zM1[e], cc = zM2[e];
        d1v[k] = av[k] - bb;
        float d2 = bb - cc;
        s12 += d1v[k] * d2;
        s22 += d2 * d2;
    }
    #pragma unroll
    for (int off = 32; off >= 1; off >>= 1) s12 += __shfl_down(s12, off, 64);
    if (lane == 0) red4[wave] = s12;
    __syncthreads();
    if (t == 0) bvalS = red4[0] + red4[1] + red4[2] + red4[3];
    __syncthreads();
    const float dot12 = bvalS;
    __syncthreads();
    #pragma unroll
    for (int off = 32; off >= 1; off >>= 1) s22 += __shfl_down(s22, off, 64);
    if (lane == 0) red4[wave] = s22;
    __syncthreads();
    if (t == 0) bvalS = red4[0] + red4[1] + red4[2] + red4[3];
    __syncthreads();
    const float dot22 = bvalS;
    __syncthreads();

    float lam = dot12 / fmaxf(dot22, 1e-30f);
    lam = fminf(fmaxf(lam, 0.0f), 0.95f);
    const float coef = lam / (1.0f - lam);
    #pragma unroll
    for (int k = 0; k < 4; ++k) ush[t + 256 * k] = av[k] + coef * d1v[k];
    __syncthreads();

    float Pv[4];
    float ps = 0.f;
    #pragma unroll
    for (int k = 0; k < 4; ++k) {
        const int e = t + 256 * k;
        Pv[k] = (e >= 1) ? 0.1f * ush[e] : 0.f;
        ps += Pv[k];
    }
    #pragma unroll
    for (int off = 32; off >= 1; off >>= 1) ps += __shfl_down(ps, off, 64);
    if (lane == 0) red4[wave] = ps;
    __syncthreads();
    if (t == 0) bvalS = (red4[0] + red4[1] + red4[2] + red4[3]) / 1023.0f;
    __syncthreads();
    const float mean = bvalS;
    __syncthreads();

    float mx = 0.f;
    #pragma unroll
    for (int k = 0; k < 4; ++k) {
        const int e = t + 256 * k;
        if (e >= 1) {
            Pv[k] = fmaxf(Pv[k] - mean, 0.f) * 100.f;
            mx = fmaxf(mx, Pv[k]);
        }
    }
    #pragma unroll
    for (int off = 32; off >= 1; off >>= 1) mx = fmaxf(mx, __shfl_down(mx, off, 64));
    if (lane == 0) red4[wave] = mx;
    __syncthreads();
    if (t == 0) bvalS = fmaxf(fmaxf(red4[0], red4[1]), fmaxf(red4[2], red4[3]));
    __syncthreads();
    const float gmax = bvalS;
    __syncthreads();

    float Ev[4];
    float es = 0.f;
    #pragma unroll
    for (int k = 0; k < 4; ++k) {
        const int e = t + 256 * k;
        Ev[k] = (e >= 1) ? expf(Pv[k] - gmax) : 0.f;
        es += Ev[k];
    }
    #pragma unroll
    for (int off = 32; off >= 1; off >>= 1) es += __shfl_down(es, off, 64);
    if (lane == 0) red4[wave] = es;
    __syncthreads();
    if (t == 0) bvalS = red4[0] + red4[1] + red4[2] + red4[3];
    __syncthreads();
    const float esum = bvalS;
    #pragma unroll
    for (int k = 0; k < 4; ++k) {
        const int e = t + 256 * k;
        if (e >= 1) out[e - 1] = Ev[k] / esum;
    }
}

extern "C" void kernel_launch(void* const* d_in, const int* in_sizes, int n_in,
                              void* d_out, int out_size, void* d_ws, size_t ws_size,
                              hipStream_t stream) {
    const float* f  = (const float*)d_in[0];
    const float* w1 = (const float*)d_in[1];
    const float* b1 = (const float*)d_in[2];
    const float* w2 = (const float*)d_in[3];
    const float* b2 = (const float*)d_in[4];
    const float* w3 = (const float*)d_in[5];
    const float* b3 = (const float*)d_in[6];
    const float* w4 = (const float*)d_in[7];
    const float* b4 = (const float*)d_in[8];
    float* ws = (float*)d_ws;

    // bar + donecnt (monotonic counters) cannot self-zero across graph replays.
    (void)hipMemsetAsync((char*)d_ws + 36096 * 4, 0, 8, stream);

    k_all<<<64, 256, 0, stream>>>(f, w1, b1, w2, b2, w3, b3, w4, b4,
                                  ws, (float*)d_out);
}

// Round 10
// 108.916 us; speedup vs baseline: 1.1243x; 1.0024x over previous
//
#include <hip/hip_runtime.h>
#include <math.h>

#define N 1024
#define DIM 128
#define LAMB 0.9f
#define INV2SIG2 (1.0f / 450.0f)   // 0.5 / sigma^2, sigma=15

typedef short v8s __attribute__((ext_vector_type(8)));
typedef float v4f __attribute__((ext_vector_type(4)));

__device__ __forceinline__ unsigned short f2bf(float x) {   // RNE float->bf16
    unsigned int u = __float_as_uint(x);
    u += 0x7FFFu + ((u >> 16) & 1u);
    return (unsigned short)(u >> 16);
}
__device__ __forceinline__ float bf2f(unsigned short h) {
    return __uint_as_float(((unsigned int)h) << 16);
}
__device__ __forceinline__ v8s cvt8(const float* p) {      // 8 fp32 -> v8s bf16
    v8s r;
    #pragma unroll
    for (int i = 0; i < 8; ++i) r[i] = (short)f2bf(p[i]);
    return r;
}

// Device-coherent store: visible device-wide once vmcnt retires (rounds 3/5/7-9).
__device__ __forceinline__ void st_dc_f32(float* p, float v) {
    asm volatile("global_store_dword %0, %1, off sc0 sc1" :: "v"(p), "v"(v) : "memory");
}
__device__ __forceinline__ void st_dc_u16(unsigned short* p, unsigned short v) {
    unsigned int vv = v;
    asm volatile("global_store_short %0, %1, off sc0 sc1" :: "v"(p), "v"(vv) : "memory");
}

// Fence-free 64-block grid barrier (validated rounds 7-9).
__device__ __forceinline__ void gridbar64(unsigned int* bar, unsigned int tgt) {
    asm volatile("s_waitcnt vmcnt(0)" ::: "memory");   // dc stores drained
    __syncthreads();
    if (threadIdx.x == 0) {
        atomicAdd(bar, 1u);
        unsigned int v;
        do {
            __builtin_amdgcn_s_sleep(1);
            v = __hip_atomic_load(bar, __ATOMIC_RELAXED, __HIP_MEMORY_SCOPE_AGENT);
        } while (v < tgt);
    }
    __syncthreads();
}

// ------------- THE kernel: 64 blocks x 1024 threads (16 waves = 4 waves/SIMD).
// MLP (8 waves, block-local) | aff-in-regs (16 waves) | mv x3 | epilogue. -------
__global__ __launch_bounds__(1024) void k_all(
    const float* __restrict__ f,
    const float* __restrict__ w1, const float* __restrict__ b1,
    const float* __restrict__ w2, const float* __restrict__ b2,
    const float* __restrict__ w3, const float* __restrict__ b3,
    const float* __restrict__ w4, const float* __restrict__ b4,
    float* __restrict__ ws, float* __restrict__ out)
{
    float* fn2   = ws + 33024;                            // 1024
    float* mag   = ws + 34048;                            // 1024
    float* total0p = ws + 35072;                          // 1 float
    unsigned int* bar     = (unsigned int*)(ws + 36096);  // memset-zeroed
    unsigned int* donecnt = (unsigned int*)(ws + 36097);  // memset-zeroed
    float* A0  = ws + 36352;                              // 1024
    float* zb0 = ws + 37376;
    float* zb1 = ws + 38400;
    float* zb2 = ws + 39424;
    unsigned short* xb = (unsigned short*)(ws + 40448);   // 1024x128 bf16

    // act rows padded to 136 ushorts (272B): b128 reads, benign bank layout (r9)
    __shared__ __align__(16) unsigned short actL[2][16][136];
    __shared__ __align__(16) float zsh[1024];             // z stage + scalar slots
    __shared__ float red[16][16];
    __shared__ float tot16[16];
    __shared__ int winner;

    const int b = blockIdx.x, t = threadIdx.x;
    const int wave = t >> 6, lane = t & 63;
    const int l15 = lane & 15, quad = lane >> 4;
    const int rbase = b * 16;

    // ======== phase 0: MLP chain, block-local; waves 0-7, one 16-col tile each ====
    if (wave < 8) {                      // layer 1: f @ w2^T + b2 -> actL[0]
        const int jt = wave * 16;
        const float* ap = f + (rbase + l15) * 128 + quad * 8;
        v8s a0 = cvt8(ap), a1 = cvt8(ap + 32), a2 = cvt8(ap + 64), a3 = cvt8(ap + 96);
        const float* wp = w2 + (jt + l15) * 128 + quad * 8;
        v4f acc = {0.f, 0.f, 0.f, 0.f};
        acc = __builtin_amdgcn_mfma_f32_16x16x32_bf16(a0, cvt8(wp), acc, 0, 0, 0);
        acc = __builtin_amdgcn_mfma_f32_16x16x32_bf16(a1, cvt8(wp + 32), acc, 0, 0, 0);
        acc = __builtin_amdgcn_mfma_f32_16x16x32_bf16(a2, cvt8(wp + 64), acc, 0, 0, 0);
        acc = __builtin_amdgcn_mfma_f32_16x16x32_bf16(a3, cvt8(wp + 96), acc, 0, 0, 0);
        const float bias = b2[jt + l15];
        #pragma unroll
        for (int reg = 0; reg < 4; ++reg)
            actL[0][quad * 4 + reg][jt + l15] = f2bf(acc[reg] + bias);
    }
    __syncthreads();
    if (wave < 8) {                      // layer 2: @ w3^T + b3 -> actL[1]
        const int jt = wave * 16;
        const unsigned short* lp = &actL[0][l15][quad * 8];
        v8s a0 = *(const v8s*)(lp), a1 = *(const v8s*)(lp + 32);
        v8s a2 = *(const v8s*)(lp + 64), a3 = *(const v8s*)(lp + 96);
        const float* wp = w3 + (jt + l15) * 128 + quad * 8;
        v4f acc = {0.f, 0.f, 0.f, 0.f};
        acc = __builtin_amdgcn_mfma_f32_16x16x32_bf16(a0, cvt8(wp), acc, 0, 0, 0);
        acc = __builtin_amdgcn_mfma_f32_16x16x32_bf16(a1, cvt8(wp + 32), acc, 0, 0, 0);
        acc = __builtin_amdgcn_mfma_f32_16x16x32_bf16(a2, cvt8(wp + 64), acc, 0, 0, 0);
        acc = __builtin_amdgcn_mfma_f32_16x16x32_bf16(a3, cvt8(wp + 96), acc, 0, 0, 0);
        const float bias = b3[jt + l15];
        #pragma unroll
        for (int reg = 0; reg < 4; ++reg)
            actL[1][quad * 4 + reg][jt + l15] = f2bf(acc[reg] + bias);
    }
    __syncthreads();
    if (wave < 8) {                      // layer 3: g = @ w4^T + b4 -> actL[0]; |g|^2
        const int jt = wave * 16;
        const unsigned short* lp = &actL[1][l15][quad * 8];
        v8s a0 = *(const v8s*)(lp), a1 = *(const v8s*)(lp + 32);
        v8s a2 = *(const v8s*)(lp + 64), a3 = *(const v8s*)(lp + 96);
        const float* wp = w4 + (jt + l15) * 128 + quad * 8;
        v4f acc = {0.f, 0.f, 0.f, 0.f};
        acc = __builtin_amdgcn_mfma_f32_16x16x32_bf16(a0, cvt8(wp), acc, 0, 0, 0);
        acc = __builtin_amdgcn_mfma_f32_16x16x32_bf16(a1, cvt8(wp + 32), acc, 0, 0, 0);
        acc = __builtin_amdgcn_mfma_f32_16x16x32_bf16(a2, cvt8(wp + 64), acc, 0, 0, 0);
        acc = __builtin_amdgcn_mfma_f32_16x16x32_bf16(a3, cvt8(wp + 96), acc, 0, 0, 0);
        const float bias = b4[jt + l15];
        float rp[4];
        #pragma unroll
        for (int reg = 0; reg < 4; ++reg) {
            float y = acc[reg] + bias;
            rp[reg] = y * y;
            actL[0][quad * 4 + reg][jt + l15] = f2bf(y);
        }
        #pragma unroll
        for (int reg = 0; reg < 4; ++reg) {
            float ss = rp[reg];
            ss += __shfl_xor(ss, 1, 64); ss += __shfl_xor(ss, 2, 64);
            ss += __shfl_xor(ss, 4, 64); ss += __shfl_xor(ss, 8, 64);
            if (l15 == 0) red[quad * 4 + reg][wave] = ss;     // fn2 partials: cols 0-7
        }
    }
    __syncthreads();
    if (wave < 8) {                      // layer 4: x = g @ w1^T + b1 -> xb; |x|^2
        const int jt = wave * 16;
        const unsigned short* lp = &actL[0][l15][quad * 8];
        v8s a0 = *(const v8s*)(lp), a1 = *(const v8s*)(lp + 32);
        v8s a2 = *(const v8s*)(lp + 64), a3 = *(const v8s*)(lp + 96);
        const float* wp = w1 + (jt + l15) * 128 + quad * 8;
        v4f acc = {0.f, 0.f, 0.f, 0.f};
        acc = __builtin_amdgcn_mfma_f32_16x16x32_bf16(a0, cvt8(wp), acc, 0, 0, 0);
        acc = __builtin_amdgcn_mfma_f32_16x16x32_bf16(a1, cvt8(wp + 32), acc, 0, 0, 0);
        acc = __builtin_amdgcn_mfma_f32_16x16x32_bf16(a2, cvt8(wp + 64), acc, 0, 0, 0);
        acc = __builtin_amdgcn_mfma_f32_16x16x32_bf16(a3, cvt8(wp + 96), acc, 0, 0, 0);
        const float bias = b1[jt + l15];
        float rp[4];
        #pragma unroll
        for (int reg = 0; reg < 4; ++reg) {
            float y = acc[reg] + bias;
            rp[reg] = y * y;
            st_dc_u16(&xb[(rbase + quad * 4 + reg) * DIM + jt + l15], f2bf(y));
        }
        #pragma unroll
        for (int reg = 0; reg < 4; ++reg) {
            float ss = rp[reg];
            ss += __shfl_xor(ss, 1, 64); ss += __shfl_xor(ss, 2, 64);
            ss += __shfl_xor(ss, 4, 64); ss += __shfl_xor(ss, 8, 64);
            if (l15 == 0) red[quad * 4 + reg][8 + wave] = ss;  // mag partials: cols 8-15
        }
    }
    __syncthreads();
    if (t < 16) {
        float sf = 0.f, sm = 0.f;
        #pragma unroll
        for (int w = 0; w < 8; ++w) { sf += red[t][w]; sm += red[t][8 + w]; }
        st_dc_f32(&fn2[rbase + t], sf);
        st_dc_f32(&mag[rbase + t], sm);
    }
    gridbar64(bar, 64);

    // ======== phase 1: affinity. 16 rows x 1024 cols; wave covers 64 cols. ========
    unsigned int abf[4][2];              // packed bf16 stripe slice (4 VGPR)
    {
        const unsigned short* ap2 = xb + (rbase + l15) * DIM + quad * 8;
        v8s afr2[4];
        #pragma unroll
        for (int kc = 0; kc < 4; ++kc) afr2[kc] = *(const v8s*)(ap2 + kc * 32);
        float rowsum[4] = {0.f, 0.f, 0.f, 0.f};
        #pragma unroll
        for (int s = 0; s < 4; ++s) {
            const int j0 = wave * 64 + s * 16;
            const unsigned short* bp = xb + (j0 + l15) * DIM + quad * 8;
            v4f acc = {0.f, 0.f, 0.f, 0.f};
            #pragma unroll
            for (int kc = 0; kc < 4; ++kc)
                acc = __builtin_amdgcn_mfma_f32_16x16x32_bf16(
                          afr2[kc], *(const v8s*)(bp + kc * 32), acc, 0, 0, 0);
            const int gj = j0 + l15;
            const float rm = 1.0f / mag[gj];
            const float fj = fn2[gj] * INV2SIG2;
            float av[4];
            #pragma unroll
            for (int reg = 0; reg < 4; ++reg) {
                const int gi = rbase + quad * 4 + reg;
                float Sv = acc[reg] * rm - 1.0f;
                av[reg] = (gi == gj) ? 0.f : __expf(-(Sv * Sv) * fj);
                rowsum[reg] += av[reg];
            }
            abf[s][0] = (unsigned int)f2bf(av[0]) | ((unsigned int)f2bf(av[1]) << 16);
            abf[s][1] = (unsigned int)f2bf(av[2]) | ((unsigned int)f2bf(av[3]) << 16);
            if (b == 0 && quad == 0) st_dc_f32(&A0[gj], av[0]);   // fp32 row 0
        }
        #pragma unroll
        for (int reg = 0; reg < 4; ++reg) {
            float ss = rowsum[reg];
            ss += __shfl_xor(ss, 1, 64); ss += __shfl_xor(ss, 2, 64);
            ss += __shfl_xor(ss, 4, 64); ss += __shfl_xor(ss, 8, 64);
            if (l15 == 0) red[quad * 4 + reg][wave] = ss;
        }
        __syncthreads();
        if (t < 16) {
            float tv = 0.f;
            #pragma unroll
            for (int w = 0; w < 16; ++w) tv += red[t][w];
            tot16[t] = tv;
            if (rbase + t == 0) st_dc_f32(total0p, tv);
        }
        __syncthreads();
    }
    gridbar64(bar, 128);

    // ======== phases 2-4: Neumann chain, stripe stays in registers ========
    const float r0s = 1.0f / fmaxf(*total0p, 1e-10f);

    #pragma unroll 1
    for (int it = 0; it < 3; ++it) {
        const float* zsrc = (it == 0) ? A0 : ((it == 1) ? zb0 : zb1);
        float* zdst = (it == 0) ? zb0 : ((it == 1) ? zb1 : zb2);
        const float zsc = (it == 0) ? r0s : 1.0f;
        if (t < 256) ((float4*)zsh)[t] = ((const float4*)zsrc)[t];   // stage z
        __syncthreads();
        float part[4] = {0.f, 0.f, 0.f, 0.f};
        #pragma unroll
        for (int s = 0; s < 4; ++s) {
            const float zv = zsh[wave * 64 + s * 16 + l15];
            part[0] += bf2f((unsigned short)(abf[s][0])) * zv;
            part[1] += bf2f((unsigned short)(abf[s][0] >> 16)) * zv;
            part[2] += bf2f((unsigned short)(abf[s][1])) * zv;
            part[3] += bf2f((unsigned short)(abf[s][1] >> 16)) * zv;
        }
        #pragma unroll
        for (int reg = 0; reg < 4; ++reg) {
            float ss = part[reg];
            ss += __shfl_xor(ss, 1, 64); ss += __shfl_xor(ss, 2, 64);
            ss += __shfl_xor(ss, 4, 64); ss += __shfl_xor(ss, 8, 64);
            if (l15 == 0) red[quad * 4 + reg][wave] = ss;
        }
        __syncthreads();
        if (t < 16) {
            const int r = rbase + t;
            float dot = 0.f;
            #pragma unroll
            for (int w = 0; w < 16; ++w) dot += red[t][w];
            float rsc = (r == 0) ? 0.f : LAMB / fmaxf(tot16[t], 1e-10f);
            float p0r = (r == 0) ? 0.f : A0[r] * r0s;
            st_dc_f32(&zdst[r], p0r + rsc * zsc * dot);
        }
        if (it == 0) gridbar64(bar, 192);
        else if (it == 1) gridbar64(bar, 256);
    }

    // last-block-done: fence-free (dc stores + vmcnt drain), 64 blocks
    asm volatile("s_waitcnt vmcnt(0)" ::: "memory");
    __syncthreads();
    if (t == 0) {
        unsigned int old = atomicAdd(donecnt, 1u);
        winner = (old == 63u) ? 1 : 0;
    }
    __syncthreads();
    if (!winner) return;

    // ---- 1024-thread Aitken + softmax epilogue, one element per thread ----
    const float av1 = zb2[t], bb = zb1[t], cc = zb0[t];
    const float d1 = av1 - bb, d2 = bb - cc;
    float s12 = d1 * d2, s22 = d2 * d2;
    #pragma unroll
    for (int off = 32; off >= 1; off >>= 1) {
        s12 += __shfl_down(s12, off, 64);
        s22 += __shfl_down(s22, off, 64);
    }
    if (lane == 0) { red[wave][0] = s12; red[wave][1] = s22; }
    __syncthreads();
    if (t == 0) {
        float a = 0.f, c = 0.f;
        #pragma unroll
        for (int w = 0; w < 16; ++w) { a += red[w][0]; c += red[w][1]; }
        zsh[0] = a; zsh[1] = c;
    }
    __syncthreads();
    float lam = zsh[0] / fmaxf(zsh[1], 1e-30f);
    lam = fminf(fmaxf(lam, 0.0f), 0.95f);
    const float coef = lam / (1.0f - lam);
    float Pv = (t >= 1) ? 0.1f * (av1 + coef * d1) : 0.f;

    float ps = Pv;
    #pragma unroll
    for (int off = 32; off >= 1; off >>= 1) ps += __shfl_down(ps, off, 64);
    if (lane == 0) red[wave][2] = ps;
    __syncthreads();
    if (t == 0) {
        float a = 0.f;
        #pragma unroll
        for (int w = 0; w < 16; ++w) a += red[w][2];
        zsh[2] = a / 1023.0f;
    }
    __syncthreads();
    const float mean = zsh[2];

    Pv = (t >= 1) ? fmaxf(Pv - mean, 0.f) * 100.f : 0.f;
    float mx = Pv;
    #pragma unroll
    for (int off = 32; off >= 1; off >>= 1) mx = fmaxf(mx, __shfl_down(mx, off, 64));
    if (lane == 0) red[wave][3] = mx;
    __syncthreads();
    if (t == 0) {
        float a = 0.f;
        #pragma unroll
        for (int w = 0; w < 16; ++w) a = fmaxf(a, red[w][3]);
        zsh[3] = a;
    }
    __syncthreads();
    const float gmax = zsh[3];

    float Ev = (t >= 1) ? expf(Pv - gmax) : 0.f;
    float es = Ev;
    #pragma unroll
    for (int off = 32; off >= 1; off >>= 1) es += __shfl_down(es, off, 64);
    if (lane == 0) red[wave][4] = es;
    __syncthreads();
    if (t == 0) {
        float a = 0.f;
        #pragma unroll
        for (int w = 0; w < 16; ++w) a += red[w][4];
        zsh[4] = a;
    }
    __syncthreads();
    if (t >= 1) out[t - 1] = Ev / zsh[4];
}

extern "C" void kernel_launch(void* const* d_in, const int* in_sizes, int n_in,
                              void* d_out, int out_size, void* d_ws, size_t ws_size,
                              hipStream_t stream) {
    const float* f  = (const float*)d_in[0];
    const float* w1 = (const float*)d_in[1];
    const float* b1 = (const float*)d_in[2];
    const float* w2 = (const float*)d_in[3];
    const float* b2 = (const float*)d_in[4];
    const float* w3 = (const float*)d_in[5];
    const float* b3 = (const float*)d_in[6];
    const float* w4 = (const float*)d_in[7];
    const float* b4 = (const float*)d_in[8];
    float* ws = (float*)d_ws;

    // bar + donecnt (monotonic counters) cannot self-zero across graph replays.
    (void)hipMemsetAsync((char*)d_ws + 36096 * 4, 0, 8, stream);

    k_all<<<64, 1024, 0, stream>>>(f, w1, b1, w2, b2, w3, b3, w4, b4,
                                   ws, (float*)d_out);
}

// Round 11
// 108.241 us; speedup vs baseline: 1.1313x; 1.0062x over previous
//
#include <hip/hip_runtime.h>
#include <math.h>

#define N 1024
#define DIM 128
#define LAMB 0.9f
#define INV2SIG2 (1.0f / 450.0f)   // 0.5 / sigma^2, sigma=15

typedef short v8s __attribute__((ext_vector_type(8)));
typedef float v4f __attribute__((ext_vector_type(4)));
typedef unsigned int v4u __attribute__((ext_vector_type(4)));

__device__ __forceinline__ unsigned short f2bf(float x) {   // RNE float->bf16
    unsigned int u = __float_as_uint(x);
    u += 0x7FFFu + ((u >> 16) & 1u);
    return (unsigned short)(u >> 16);
}
__device__ __forceinline__ float bf2f(unsigned short h) {
    return __uint_as_float(((unsigned int)h) << 16);
}
__device__ __forceinline__ v8s cvt8(const float* p) {      // 8 fp32 -> v8s bf16
    v8s r;
    #pragma unroll
    for (int i = 0; i < 8; ++i) r[i] = (short)f2bf(p[i]);
    return r;
}

// Device-coherent stores: visible device-wide once vmcnt retires (rounds 3/5/7-10).
__device__ __forceinline__ void st_dc_f32(float* p, float v) {
    asm volatile("global_store_dword %0, %1, off sc0 sc1" :: "v"(p), "v"(v) : "memory");
}
__device__ __forceinline__ void st_dc_b128(void* p, v4u v) {
    asm volatile("global_store_dwordx4 %0, %1, off sc0 sc1" :: "v"(p), "v"(v) : "memory");
}

// Fence-free 64-block grid barrier (validated rounds 7-10).
__device__ __forceinline__ void gridbar64(unsigned int* bar, unsigned int tgt) {
    asm volatile("s_waitcnt vmcnt(0)" ::: "memory");   // dc stores drained
    __syncthreads();
    if (threadIdx.x == 0) {
        atomicAdd(bar, 1u);
        unsigned int v;
        do {
            __builtin_amdgcn_s_sleep(1);
            v = __hip_atomic_load(bar, __ATOMIC_RELAXED, __HIP_MEMORY_SCOPE_AGENT);
        } while (v < tgt);
    }
    __syncthreads();
}

// ------------- THE kernel: 64 blocks x 1024 threads. 4 global sync events:
// MLP -> E1 -> aff(+redundant row-0 => mv0 needs NO sync) -> mv0 -> E2 -> mv1
// -> E3 -> mv2 -> done -> epilogue. -------
__global__ __launch_bounds__(1024) void k_all(
    const float* __restrict__ f,
    const float* __restrict__ w1, const float* __restrict__ b1,
    const float* __restrict__ w2, const float* __restrict__ b2,
    const float* __restrict__ w3, const float* __restrict__ b3,
    const float* __restrict__ w4, const float* __restrict__ b4,
    float* __restrict__ ws, float* __restrict__ out)
{
    float* fn2   = ws + 33024;                            // 1024
    float* mag   = ws + 34048;                            // 1024
    unsigned int* bar     = (unsigned int*)(ws + 36096);  // memset-zeroed
    unsigned int* donecnt = (unsigned int*)(ws + 36097);  // memset-zeroed
    float* zb0 = ws + 37376;
    float* zb1 = ws + 38400;
    float* zb2 = ws + 39424;
    unsigned short* xb = (unsigned short*)(ws + 40448);   // 1024x128 bf16

    __shared__ __align__(16) unsigned short actL[2][16][136];  // 272B rows
    __shared__ __align__(16) float zsh[1024];
    __shared__ __align__(16) float a0sh[1024];            // row 0 of A, block-local
    __shared__ float red[16][16];
    __shared__ float redz[16];
    __shared__ float tot16[16];
    __shared__ float tot0sh;
    __shared__ int winner;

    const int b = blockIdx.x, t = threadIdx.x;
    const int wave = t >> 6, lane = t & 63;
    const int l15 = lane & 15, quad = lane >> 4;
    const int rbase = b * 16;

    // ======== phase 0: MLP chain, block-local; waves 0-7, one 16-col tile each ====
    if (wave < 8) {                      // layer 1: f @ w2^T + b2 -> actL[0]
        const int jt = wave * 16;
        const float* ap = f + (rbase + l15) * 128 + quad * 8;
        v8s a0 = cvt8(ap), a1 = cvt8(ap + 32), a2 = cvt8(ap + 64), a3 = cvt8(ap + 96);
        const float* wp = w2 + (jt + l15) * 128 + quad * 8;
        v4f acc = {0.f, 0.f, 0.f, 0.f};
        acc = __builtin_amdgcn_mfma_f32_16x16x32_bf16(a0, cvt8(wp), acc, 0, 0, 0);
        acc = __builtin_amdgcn_mfma_f32_16x16x32_bf16(a1, cvt8(wp + 32), acc, 0, 0, 0);
        acc = __builtin_amdgcn_mfma_f32_16x16x32_bf16(a2, cvt8(wp + 64), acc, 0, 0, 0);
        acc = __builtin_amdgcn_mfma_f32_16x16x32_bf16(a3, cvt8(wp + 96), acc, 0, 0, 0);
        const float bias = b2[jt + l15];
        #pragma unroll
        for (int reg = 0; reg < 4; ++reg)
            actL[0][quad * 4 + reg][jt + l15] = f2bf(acc[reg] + bias);
    }
    __syncthreads();
    if (wave < 8) {                      // layer 2: @ w3^T + b3 -> actL[1]
        const int jt = wave * 16;
        const unsigned short* lp = &actL[0][l15][quad * 8];
        v8s a0 = *(const v8s*)(lp), a1 = *(const v8s*)(lp + 32);
        v8s a2 = *(const v8s*)(lp + 64), a3 = *(const v8s*)(lp + 96);
        const float* wp = w3 + (jt + l15) * 128 + quad * 8;
        v4f acc = {0.f, 0.f, 0.f, 0.f};
        acc = __builtin_amdgcn_mfma_f32_16x16x32_bf16(a0, cvt8(wp), acc, 0, 0, 0);
        acc = __builtin_amdgcn_mfma_f32_16x16x32_bf16(a1, cvt8(wp + 32), acc, 0, 0, 0);
        acc = __builtin_amdgcn_mfma_f32_16x16x32_bf16(a2, cvt8(wp + 64), acc, 0, 0, 0);
        acc = __builtin_amdgcn_mfma_f32_16x16x32_bf16(a3, cvt8(wp + 96), acc, 0, 0, 0);
        const float bias = b3[jt + l15];
        #pragma unroll
        for (int reg = 0; reg < 4; ++reg)
            actL[1][quad * 4 + reg][jt + l15] = f2bf(acc[reg] + bias);
    }
    __syncthreads();
    if (wave < 8) {                      // layer 3: g = @ w4^T + b4 -> actL[0]; |g|^2
        const int jt = wave * 16;
        const unsigned short* lp = &actL[1][l15][quad * 8];
        v8s a0 = *(const v8s*)(lp), a1 = *(const v8s*)(lp + 32);
        v8s a2 = *(const v8s*)(lp + 64), a3 = *(const v8s*)(lp + 96);
        const float* wp = w4 + (jt + l15) * 128 + quad * 8;
        v4f acc = {0.f, 0.f, 0.f, 0.f};
        acc = __builtin_amdgcn_mfma_f32_16x16x32_bf16(a0, cvt8(wp), acc, 0, 0, 0);
        acc = __builtin_amdgcn_mfma_f32_16x16x32_bf16(a1, cvt8(wp + 32), acc, 0, 0, 0);
        acc = __builtin_amdgcn_mfma_f32_16x16x32_bf16(a2, cvt8(wp + 64), acc, 0, 0, 0);
        acc = __builtin_amdgcn_mfma_f32_16x16x32_bf16(a3, cvt8(wp + 96), acc, 0, 0, 0);
        const float bias = b4[jt + l15];
        float rp[4];
        #pragma unroll
        for (int reg = 0; reg < 4; ++reg) {
            float y = acc[reg] + bias;
            rp[reg] = y * y;
            actL[0][quad * 4 + reg][jt + l15] = f2bf(y);
        }
        #pragma unroll
        for (int reg = 0; reg < 4; ++reg) {
            float ss = rp[reg];
            ss += __shfl_xor(ss, 1, 64); ss += __shfl_xor(ss, 2, 64);
            ss += __shfl_xor(ss, 4, 64); ss += __shfl_xor(ss, 8, 64);
            if (l15 == 0) red[quad * 4 + reg][wave] = ss;     // fn2 partials: cols 0-7
        }
    }
    __syncthreads();
    if (wave < 8) {                      // layer 4: x = g @ w1^T + b1 -> actL[1]; |x|^2
        const int jt = wave * 16;
        const unsigned short* lp = &actL[0][l15][quad * 8];
        v8s a0 = *(const v8s*)(lp), a1 = *(const v8s*)(lp + 32);
        v8s a2 = *(const v8s*)(lp + 64), a3 = *(const v8s*)(lp + 96);
        const float* wp = w1 + (jt + l15) * 128 + quad * 8;
        v4f acc = {0.f, 0.f, 0.f, 0.f};
        acc = __builtin_amdgcn_mfma_f32_16x16x32_bf16(a0, cvt8(wp), acc, 0, 0, 0);
        acc = __builtin_amdgcn_mfma_f32_16x16x32_bf16(a1, cvt8(wp + 32), acc, 0, 0, 0);
        acc = __builtin_amdgcn_mfma_f32_16x16x32_bf16(a2, cvt8(wp + 64), acc, 0, 0, 0);
        acc = __builtin_amdgcn_mfma_f32_16x16x32_bf16(a3, cvt8(wp + 96), acc, 0, 0, 0);
        const float bias = b1[jt + l15];
        float rp[4];
        #pragma unroll
        for (int reg = 0; reg < 4; ++reg) {
            float y = acc[reg] + bias;
            rp[reg] = y * y;
            actL[1][quad * 4 + reg][jt + l15] = f2bf(y);   // LDS, not scattered global
        }
        #pragma unroll
        for (int reg = 0; reg < 4; ++reg) {
            float ss = rp[reg];
            ss += __shfl_xor(ss, 1, 64); ss += __shfl_xor(ss, 2, 64);
            ss += __shfl_xor(ss, 4, 64); ss += __shfl_xor(ss, 8, 64);
            if (l15 == 0) red[quad * 4 + reg][8 + wave] = ss;  // mag partials: cols 8-15
        }
    }
    __syncthreads();
    // coalesced xb flush: 256 x 16B dc stores (vs 8192 x 2B scattered — drain cost)
    if (t < 256) {
        const int row = t >> 4, chunk = t & 15;
        v4u v = *(const v4u*)&actL[1][row][chunk * 8];
        st_dc_b128(&xb[(rbase + row) * DIM + chunk * 8], v);
    }
    if (t < 16) {
        float sf = 0.f, sm = 0.f;
        #pragma unroll
        for (int w = 0; w < 8; ++w) { sf += red[t][w]; sm += red[t][8 + w]; }
        st_dc_f32(&fn2[rbase + t], sf);
        st_dc_f32(&mag[rbase + t], sm);
    }
    gridbar64(bar, 64);                  // E1: xb/fn2/mag globally visible

    // ======== phase 1: affinity, 16 rows x 1024 cols; + redundant row 0 ========
    unsigned int abf[4][2];              // packed bf16 stripe slice
    {
        // A-frags for own rows from LDS (identical bf16 values to xb)
        const unsigned short* lp = &actL[1][l15][quad * 8];
        v8s afr2[4];
        #pragma unroll
        for (int kc = 0; kc < 4; ++kc) afr2[kc] = *(const v8s*)(lp + kc * 32);
        // broadcast-A frags: every A-row = x_0  (row 0 of xb, 16B/lane shared)
        const unsigned short* x0p = xb + quad * 8;
        v8s xfr[4];
        #pragma unroll
        for (int kc = 0; kc < 4; ++kc) xfr[kc] = *(const v8s*)(x0p + kc * 32);

        float rowsum[4] = {0.f, 0.f, 0.f, 0.f};
        #pragma unroll
        for (int s = 0; s < 4; ++s) {
            const int j0 = wave * 64 + s * 16;
            const unsigned short* bp = xb + (j0 + l15) * DIM + quad * 8;
            v8s bfr[4];
            #pragma unroll
            for (int kc = 0; kc < 4; ++kc) bfr[kc] = *(const v8s*)(bp + kc * 32);
            v4f acc  = {0.f, 0.f, 0.f, 0.f};
            v4f acc0 = {0.f, 0.f, 0.f, 0.f};
            #pragma unroll
            for (int kc = 0; kc < 4; ++kc) {
                acc  = __builtin_amdgcn_mfma_f32_16x16x32_bf16(afr2[kc], bfr[kc], acc, 0, 0, 0);
                acc0 = __builtin_amdgcn_mfma_f32_16x16x32_bf16(xfr[kc],  bfr[kc], acc0, 0, 0, 0);
            }
            const int gj = j0 + l15;
            const float rm = 1.0f / mag[gj];
            const float fj = fn2[gj] * INV2SIG2;
            float av[4];
            #pragma unroll
            for (int reg = 0; reg < 4; ++reg) {
                const int gi = rbase + quad * 4 + reg;
                float Sv = acc[reg] * rm - 1.0f;
                av[reg] = (gi == gj) ? 0.f : __expf(-(Sv * Sv) * fj);
                rowsum[reg] += av[reg];
            }
            abf[s][0] = (unsigned int)f2bf(av[0]) | ((unsigned int)f2bf(av[1]) << 16);
            abf[s][1] = (unsigned int)f2bf(av[2]) | ((unsigned int)f2bf(av[3]) << 16);
            if (quad == 0) {             // row-0 value for col gj (all rows identical)
                float Sv0 = acc0[0] * rm - 1.0f;
                a0sh[gj] = (gj == 0) ? 0.f : __expf(-(Sv0 * Sv0) * fj);
            }
        }
        #pragma unroll
        for (int reg = 0; reg < 4; ++reg) {
            float ss = rowsum[reg];
            ss += __shfl_xor(ss, 1, 64); ss += __shfl_xor(ss, 2, 64);
            ss += __shfl_xor(ss, 4, 64); ss += __shfl_xor(ss, 8, 64);
            if (l15 == 0) red[quad * 4 + reg][wave] = ss;
        }
        __syncthreads();                 // red + a0sh complete
        if (t < 16) {
            float tv = 0.f;
            #pragma unroll
            for (int w = 0; w < 16; ++w) tv += red[t][w];
            tot16[t] = tv;
        }
        float a0v = a0sh[t];             // total0 = sum(a0sh), block-local
        #pragma unroll
        for (int off = 32; off >= 1; off >>= 1) a0v += __shfl_down(a0v, off, 64);
        if (lane == 0) redz[wave] = a0v;
        __syncthreads();
        if (t == 0) {
            float s0 = 0.f;
            #pragma unroll
            for (int w = 0; w < 16; ++w) s0 += redz[w];
            tot0sh = s0;
        }
        __syncthreads();
    }

    // ======== mv0: NO global sync needed (a0sh/tot0/tot16/stripe all local) ======
    const float r0s = 1.0f / fmaxf(tot0sh, 1e-10f);
    {
        float part[4] = {0.f, 0.f, 0.f, 0.f};
        #pragma unroll
        for (int s = 0; s < 4; ++s) {
            const float zv = a0sh[wave * 64 + s * 16 + l15];
            part[0] += bf2f((unsigned short)(abf[s][0])) * zv;
            part[1] += bf2f((unsigned short)(abf[s][0] >> 16)) * zv;
            part[2] += bf2f((unsigned short)(abf[s][1])) * zv;
            part[3] += bf2f((unsigned short)(abf[s][1] >> 16)) * zv;
        }
        #pragma unroll
        for (int reg = 0; reg < 4; ++reg) {
            float ss = part[reg];
            ss += __shfl_xor(ss, 1, 64); ss += __shfl_xor(ss, 2, 64);
            ss += __shfl_xor(ss, 4, 64); ss += __shfl_xor(ss, 8, 64);
            if (l15 == 0) red[quad * 4 + reg][wave] = ss;
        }
        __syncthreads();
        if (t < 16) {
            const int r = rbase + t;
            float dot = 0.f;
            #pragma unroll
            for (int w = 0; w < 16; ++w) dot += red[t][w];
            float rsc = (r == 0) ? 0.f : LAMB / fmaxf(tot16[t], 1e-10f);
            float p0r = (r == 0) ? 0.f : a0sh[r] * r0s;
            st_dc_f32(&zb0[r], p0r + rsc * r0s * dot);
        }
    }
    gridbar64(bar, 128);                 // E2: zb0 visible

    // ======== mv1 / mv2 ========
    #pragma unroll 1
    for (int it = 1; it < 3; ++it) {
        const float* zsrc = (it == 1) ? zb0 : zb1;
        float* zdst = (it == 1) ? zb1 : zb2;
        if (t < 256) ((float4*)zsh)[t] = ((const float4*)zsrc)[t];
        __syncthreads();
        float part[4] = {0.f, 0.f, 0.f, 0.f};
        #pragma unroll
        for (int s = 0; s < 4; ++s) {
            const float zv = zsh[wave * 64 + s * 16 + l15];
            part[0] += bf2f((unsigned short)(abf[s][0])) * zv;
            part[1] += bf2f((unsigned short)(abf[s][0] >> 16)) * zv;
            part[2] += bf2f((unsigned short)(abf[s][1])) * zv;
            part[3] += bf2f((unsigned short)(abf[s][1] >> 16)) * zv;
        }
        #pragma unroll
        for (int reg = 0; reg < 4; ++reg) {
            float ss = part[reg];
            ss += __shfl_xor(ss, 1, 64); ss += __shfl_xor(ss, 2, 64);
            ss += __shfl_xor(ss, 4, 64); ss += __shfl_xor(ss, 8, 64);
            if (l15 == 0) red[quad * 4 + reg][wave] = ss;
        }
        __syncthreads();
        if (t < 16) {
            const int r = rbase + t;
            float dot = 0.f;
            #pragma unroll
            for (int w = 0; w < 16; ++w) dot += red[t][w];
            float rsc = (r == 0) ? 0.f : LAMB / fmaxf(tot16[t], 1e-10f);
            float p0r = (r == 0) ? 0.f : a0sh[r] * r0s;
            st_dc_f32(&zdst[r], p0r + rsc * dot);
        }
        if (it == 1) gridbar64(bar, 192);   // E3: zb1 visible
    }

    // done handshake (E4): fence-free, 64 blocks
    asm volatile("s_waitcnt vmcnt(0)" ::: "memory");
    __syncthreads();
    if (t == 0) {
        unsigned int old = atomicAdd(donecnt, 1u);
        winner = (old == 63u) ? 1 : 0;
    }
    __syncthreads();
    if (!winner) return;

    // ---- 1024-thread Aitken + softmax epilogue, one element per thread ----
    const float av1 = zb2[t], bb = zb1[t], cc = zb0[t];
    const float d1 = av1 - bb, d2 = bb - cc;
    float s12 = d1 * d2, s22 = d2 * d2;
    #pragma unroll
    for (int off = 32; off >= 1; off >>= 1) {
        s12 += __shfl_down(s12, off, 64);
        s22 += __shfl_down(s22, off, 64);
    }
    if (lane == 0) { red[wave][0] = s12; red[wave][1] = s22; }
    __syncthreads();
    if (t == 0) {
        float a = 0.f, c = 0.f;
        #pragma unroll
        for (int w = 0; w < 16; ++w) { a += red[w][0]; c += red[w][1]; }
        zsh[0] = a; zsh[1] = c;
    }
    __syncthreads();
    float lam = zsh[0] / fmaxf(zsh[1], 1e-30f);
    lam = fminf(fmaxf(lam, 0.0f), 0.95f);
    const float coef = lam / (1.0f - lam);
    float Pv = (t >= 1) ? 0.1f * (av1 + coef * d1) : 0.f;

    float ps = Pv;
    #pragma unroll
    for (int off = 32; off >= 1; off >>= 1) ps += __shfl_down(ps, off, 64);
    if (lane == 0) red[wave][2] = ps;
    __syncthreads();
    if (t == 0) {
        float a = 0.f;
        #pragma unroll
        for (int w = 0; w < 16; ++w) a += red[w][2];
        zsh[2] = a / 1023.0f;
    }
    __syncthreads();
    const float mean = zsh[2];

    Pv = (t >= 1) ? fmaxf(Pv - mean, 0.f) * 100.f : 0.f;
    float mx = Pv;
    #pragma unroll
    for (int off = 32; off >= 1; off >>= 1) mx = fmaxf(mx, __shfl_down(mx, off, 64));
    if (lane == 0) red[wave][3] = mx;
    __syncthreads();
    if (t == 0) {
        float a = 0.f;
        #pragma unroll
        for (int w = 0; w < 16; ++w) a = fmaxf(a, red[w][3]);
        zsh[3] = a;
    }
    __syncthreads();
    const float gmax = zsh[3];

    float Ev = (t >= 1) ? expf(Pv - gmax) : 0.f;
    float es = Ev;
    #pragma unroll
    for (int off = 32; off >= 1; off >>= 1) es += __shfl_down(es, off, 64);
    if (lane == 0) red[wave][4] = es;
    __syncthreads();
    if (t == 0) {
        float a = 0.f;
        #pragma unroll
        for (int w = 0; w < 16; ++w) a += red[w][4];
        zsh[4] = a;
    }
    __syncthreads();
    if (t >= 1) out[t - 1] = Ev / zsh[4];
}

extern "C" void kernel_launch(void* const* d_in, const int* in_sizes, int n_in,
                              void* d_out, int out_size, void* d_ws, size_t ws_size,
                              hipStream_t stream) {
    const float* f  = (const float*)d_in[0];
    const float* w1 = (const float*)d_in[1];
    const float* b1 = (const float*)d_in[2];
    const float* w2 = (const float*)d_in[3];
    const float* b2 = (const float*)d_in[4];
    const float* w3 = (const float*)d_in[5];
    const float* b3 = (const float*)d_in[6];
    const float* w4 = (const float*)d_in[7];
    const float* b4 = (const float*)d_in[8];
    float* ws = (float*)d_ws;

    // bar + donecnt (monotonic counters) cannot self-zero across graph replays.
    (void)hipMemsetAsync((char*)d_ws + 36096 * 4, 0, 8, stream);

    k_all<<<64, 1024, 0, stream>>>(f, w1, b1, w2, b2, w3, b3, w4, b4,
                                   ws, (float*)d_out);
}

// Round 12
// 105.700 us; speedup vs baseline: 1.1585x; 1.0240x over previous
//
#include <hip/hip_runtime.h>
#include <math.h>

#define N 1024
#define DIM 128
#define LAMB 0.9f
#define INV2SIG2 (1.0f / 450.0f)   // 0.5 / sigma^2, sigma=15

typedef short v8s __attribute__((ext_vector_type(8)));
typedef float v4f __attribute__((ext_vector_type(4)));
typedef unsigned int v4u __attribute__((ext_vector_type(4)));

__device__ __forceinline__ unsigned short f2bf(float x) {   // RNE float->bf16
    unsigned int u = __float_as_uint(x);
    u += 0x7FFFu + ((u >> 16) & 1u);
    return (unsigned short)(u >> 16);
}
__device__ __forceinline__ float bf2f(unsigned short h) {
    return __uint_as_float(((unsigned int)h) << 16);
}
__device__ __forceinline__ v8s cvt8(const float* p) {      // 8 fp32 -> v8s bf16
    v8s r;
    #pragma unroll
    for (int i = 0; i < 8; ++i) r[i] = (short)f2bf(p[i]);
    return r;
}

// Device-coherent store (validated rounds 3/5/7-11): visible once vmcnt retires.
__device__ __forceinline__ void st_dc_f32(float* p, float v) {
    asm volatile("global_store_dword %0, %1, off sc0 sc1" :: "v"(p), "v"(v) : "memory");
}

// Fence-free 64-block grid barrier (validated rounds 7-11).
__device__ __forceinline__ void gridbar64(unsigned int* bar, unsigned int tgt) {
    asm volatile("s_waitcnt vmcnt(0)" ::: "memory");   // dc stores drained
    __syncthreads();
    if (threadIdx.x == 0) {
        atomicAdd(bar, 1u);
        unsigned int v;
        do {
            __builtin_amdgcn_s_sleep(1);
            v = __hip_atomic_load(bar, __ATOMIC_RELAXED, __HIP_MEMORY_SCOPE_AGENT);
        } while (v < tgt);
    }
    __syncthreads();
}

// ---------------- K0: 4-layer MLP, row-local (NO compose). 64 blocks x 1024.
// Block owns rows 16b..16b+15: f @W2^T -> @W3^T -> @W4^T (g, fn2) -> @W1^T (x, mag).
// Writes xb (coalesced), fn2, mag; zeroes total for k_aff's atomics. ----------
__global__ __launch_bounds__(1024) void k_mlp(
    const float* __restrict__ f,
    const float* __restrict__ w1, const float* __restrict__ b1,
    const float* __restrict__ w2, const float* __restrict__ b2,
    const float* __restrict__ w3, const float* __restrict__ b3,
    const float* __restrict__ w4, const float* __restrict__ b4,
    unsigned short* __restrict__ xb, float* __restrict__ fn2,
    float* __restrict__ mag, float* __restrict__ total)
{
    __shared__ __align__(16) unsigned short actL[2][16][136];  // 272B rows
    __shared__ float red[16][16];

    const int b = blockIdx.x, t = threadIdx.x;
    const int wave = t >> 6, lane = t & 63;
    const int l15 = lane & 15, quad = lane >> 4;
    const int rbase = b * 16;

    if (t < 16) total[rbase + t] = 0.f;  // k_aff accumulates into this

    if (wave < 8) {                      // layer 1: f @ w2^T + b2 -> actL[0]
        const int jt = wave * 16;
        const float* ap = f + (rbase + l15) * 128 + quad * 8;
        v8s a0 = cvt8(ap), a1 = cvt8(ap + 32), a2 = cvt8(ap + 64), a3 = cvt8(ap + 96);
        const float* wp = w2 + (jt + l15) * 128 + quad * 8;
        v4f acc = {0.f, 0.f, 0.f, 0.f};
        acc = __builtin_amdgcn_mfma_f32_16x16x32_bf16(a0, cvt8(wp), acc, 0, 0, 0);
        acc = __builtin_amdgcn_mfma_f32_16x16x32_bf16(a1, cvt8(wp + 32), acc, 0, 0, 0);
        acc = __builtin_amdgcn_mfma_f32_16x16x32_bf16(a2, cvt8(wp + 64), acc, 0, 0, 0);
        acc = __builtin_amdgcn_mfma_f32_16x16x32_bf16(a3, cvt8(wp + 96), acc, 0, 0, 0);
        const float bias = b2[jt + l15];
        #pragma unroll
        for (int reg = 0; reg < 4; ++reg)
            actL[0][quad * 4 + reg][jt + l15] = f2bf(acc[reg] + bias);
    }
    __syncthreads();
    if (wave < 8) {                      // layer 2: @ w3^T + b3 -> actL[1]
        const int jt = wave * 16;
        const unsigned short* lp = &actL[0][l15][quad * 8];
        v8s a0 = *(const v8s*)(lp), a1 = *(const v8s*)(lp + 32);
        v8s a2 = *(const v8s*)(lp + 64), a3 = *(const v8s*)(lp + 96);
        const float* wp = w3 + (jt + l15) * 128 + quad * 8;
        v4f acc = {0.f, 0.f, 0.f, 0.f};
        acc = __builtin_amdgcn_mfma_f32_16x16x32_bf16(a0, cvt8(wp), acc, 0, 0, 0);
        acc = __builtin_amdgcn_mfma_f32_16x16x32_bf16(a1, cvt8(wp + 32), acc, 0, 0, 0);
        acc = __builtin_amdgcn_mfma_f32_16x16x32_bf16(a2, cvt8(wp + 64), acc, 0, 0, 0);
        acc = __builtin_amdgcn_mfma_f32_16x16x32_bf16(a3, cvt8(wp + 96), acc, 0, 0, 0);
        const float bias = b3[jt + l15];
        #pragma unroll
        for (int reg = 0; reg < 4; ++reg)
            actL[1][quad * 4 + reg][jt + l15] = f2bf(acc[reg] + bias);
    }
    __syncthreads();
    if (wave < 8) {                      // layer 3: g = @ w4^T + b4 -> actL[0]; |g|^2
        const int jt = wave * 16;
        const unsigned short* lp = &actL[1][l15][quad * 8];
        v8s a0 = *(const v8s*)(lp), a1 = *(const v8s*)(lp + 32);
        v8s a2 = *(const v8s*)(lp + 64), a3 = *(const v8s*)(lp + 96);
        const float* wp = w4 + (jt + l15) * 128 + quad * 8;
        v4f acc = {0.f, 0.f, 0.f, 0.f};
        acc = __builtin_amdgcn_mfma_f32_16x16x32_bf16(a0, cvt8(wp), acc, 0, 0, 0);
        acc = __builtin_amdgcn_mfma_f32_16x16x32_bf16(a1, cvt8(wp + 32), acc, 0, 0, 0);
        acc = __builtin_amdgcn_mfma_f32_16x16x32_bf16(a2, cvt8(wp + 64), acc, 0, 0, 0);
        acc = __builtin_amdgcn_mfma_f32_16x16x32_bf16(a3, cvt8(wp + 96), acc, 0, 0, 0);
        const float bias = b4[jt + l15];
        float rp[4];
        #pragma unroll
        for (int reg = 0; reg < 4; ++reg) {
            float y = acc[reg] + bias;
            rp[reg] = y * y;
            actL[0][quad * 4 + reg][jt + l15] = f2bf(y);
        }
        #pragma unroll
        for (int reg = 0; reg < 4; ++reg) {
            float ss = rp[reg];
            ss += __shfl_xor(ss, 1, 64); ss += __shfl_xor(ss, 2, 64);
            ss += __shfl_xor(ss, 4, 64); ss += __shfl_xor(ss, 8, 64);
            if (l15 == 0) red[quad * 4 + reg][wave] = ss;     // fn2 partials
        }
    }
    __syncthreads();
    if (wave < 8) {                      // layer 4: x = g @ w1^T + b1 -> actL[1]; |x|^2
        const int jt = wave * 16;
        const unsigned short* lp = &actL[0][l15][quad * 8];
        v8s a0 = *(const v8s*)(lp), a1 = *(const v8s*)(lp + 32);
        v8s a2 = *(const v8s*)(lp + 64), a3 = *(const v8s*)(lp + 96);
        const float* wp = w1 + (jt + l15) * 128 + quad * 8;
        v4f acc = {0.f, 0.f, 0.f, 0.f};
        acc = __builtin_amdgcn_mfma_f32_16x16x32_bf16(a0, cvt8(wp), acc, 0, 0, 0);
        acc = __builtin_amdgcn_mfma_f32_16x16x32_bf16(a1, cvt8(wp + 32), acc, 0, 0, 0);
        acc = __builtin_amdgcn_mfma_f32_16x16x32_bf16(a2, cvt8(wp + 64), acc, 0, 0, 0);
        acc = __builtin_amdgcn_mfma_f32_16x16x32_bf16(a3, cvt8(wp + 96), acc, 0, 0, 0);
        const float bias = b1[jt + l15];
        float rp[4];
        #pragma unroll
        for (int reg = 0; reg < 4; ++reg) {
            float y = acc[reg] + bias;
            rp[reg] = y * y;
            actL[1][quad * 4 + reg][jt + l15] = f2bf(y);
        }
        #pragma unroll
        for (int reg = 0; reg < 4; ++reg) {
            float ss = rp[reg];
            ss += __shfl_xor(ss, 1, 64); ss += __shfl_xor(ss, 2, 64);
            ss += __shfl_xor(ss, 4, 64); ss += __shfl_xor(ss, 8, 64);
            if (l15 == 0) red[quad * 4 + reg][8 + wave] = ss;  // mag partials
        }
    }
    __syncthreads();
    if (t < 256) {                       // coalesced xb flush: 256 x 16B
        const int row = t >> 4, chunk = t & 15;
        *(v4u*)&xb[(rbase + row) * DIM + chunk * 8] = *(const v4u*)&actL[1][row][chunk * 8];
    }
    if (t < 16) {
        float sf = 0.f, sm = 0.f;
        #pragma unroll
        for (int w = 0; w < 8; ++w) { sf += red[t][w]; sm += red[t][8 + w]; }
        fn2[rbase + t] = sf;
        mag[rbase + t] = sm;
    }
}

// ---------------- K1: 256-block affinity -> Bu (UNSCALED bf16), totals, A0 ----------
__global__ __launch_bounds__(256) void k_aff(
    const unsigned short* __restrict__ xb, const float* __restrict__ mag,
    const float* __restrict__ fn2,
    unsigned short* __restrict__ Bu, float* __restrict__ A0,
    float* __restrict__ total)
{
    const int b = blockIdx.x, t = threadIdx.x;
    const int wave = t >> 6, lane = t & 63;
    const int l15 = lane & 15, quad = lane >> 4;
    const int slab = b >> 2;            // rows slab*16..+16
    const int qtr  = b & 3;             // j-quarter (256 cols)
    const int i0 = slab * 16;

    const unsigned short* ap = xb + (i0 + l15) * DIM + quad * 8;
    v8s afr[4];
    #pragma unroll
    for (int kc = 0; kc < 4; ++kc) afr[kc] = *(const v8s*)(ap + kc * 32);

    float rowsum[4] = {0.f, 0.f, 0.f, 0.f};
    #pragma unroll
    for (int s = 0; s < 4; ++s) {
        const int j0 = (qtr * 16 + wave * 4 + s) * 16;
        const unsigned short* bp = xb + (j0 + l15) * DIM + quad * 8;
        v4f acc = {0.f, 0.f, 0.f, 0.f};
        #pragma unroll
        for (int kc = 0; kc < 4; ++kc)
            acc = __builtin_amdgcn_mfma_f32_16x16x32_bf16(
                      afr[kc], *(const v8s*)(bp + kc * 32), acc, 0, 0, 0);
        const int gj = j0 + l15;
        const float rm = 1.0f / mag[gj];
        const float fj = fn2[gj] * INV2SIG2;
        #pragma unroll
        for (int reg = 0; reg < 4; ++reg) {
            const int gi = i0 + quad * 4 + reg;
            float Sv = acc[reg] * rm - 1.0f;
            float a = (gi == gj) ? 0.f : __expf(-(Sv * Sv) * fj);
            Bu[gi * N + gj] = f2bf(a);
            rowsum[reg] += a;
            if (gi == 0) A0[gj] = a;    // fp32 row 0 for P0
        }
    }
    #pragma unroll
    for (int reg = 0; reg < 4; ++reg) {
        float ss = rowsum[reg];
        ss += __shfl_xor(ss, 1, 64); ss += __shfl_xor(ss, 2, 64);
        ss += __shfl_xor(ss, 4, 64); ss += __shfl_xor(ss, 8, 64);
        if (l15 == 0) atomicAdd(&total[i0 + quad * 4 + reg], ss);
    }
}

// ---- partial dot for one cached Bu row against z held in registers ----
__device__ __forceinline__ float dotp(uint4 ma, uint4 mb,
                                      float4 z0, float4 z1, float4 z2, float4 z3) {
    float acc = 0.f;
    acc += bf2f((unsigned short)(ma.x)) * z0.x + bf2f((unsigned short)(ma.x >> 16)) * z0.y;
    acc += bf2f((unsigned short)(ma.y)) * z0.z + bf2f((unsigned short)(ma.y >> 16)) * z0.w;
    acc += bf2f((unsigned short)(ma.z)) * z1.x + bf2f((unsigned short)(ma.z >> 16)) * z1.y;
    acc += bf2f((unsigned short)(ma.w)) * z1.z + bf2f((unsigned short)(ma.w >> 16)) * z1.w;
    acc += bf2f((unsigned short)(mb.x)) * z2.x + bf2f((unsigned short)(mb.x >> 16)) * z2.y;
    acc += bf2f((unsigned short)(mb.y)) * z2.z + bf2f((unsigned short)(mb.y >> 16)) * z2.w;
    acc += bf2f((unsigned short)(mb.z)) * z3.x + bf2f((unsigned short)(mb.z >> 16)) * z3.y;
    acc += bf2f((unsigned short)(mb.w)) * z3.z + bf2f((unsigned short)(mb.w >> 16)) * z3.w;
    return acc;
}

// ---------------- K2: all 3 Neumann matvecs in ONE 64-block kernel + epilogue ----
// (round-7 verified: 16 rows/block, Bu rows cached in regs, 2 cheap barriers)
__global__ __launch_bounds__(256) void k_mv3(
    const unsigned short* __restrict__ M, const float* __restrict__ A0,
    const float* __restrict__ total,
    float* __restrict__ zb0, float* __restrict__ zb1, float* __restrict__ zb2,
    unsigned int* __restrict__ bar, unsigned int* __restrict__ donecnt,
    float* __restrict__ out)
{
    __shared__ float red4[4];
    __shared__ float bvalS;
    __shared__ float ush[1024];
    __shared__ int winner;
    const int b = blockIdx.x, t = threadIdx.x;
    const int wave = t >> 6, lane = t & 63;
    const int rbase = b * 16 + wave * 4;

    const float r0s = 1.0f / fmaxf(total[0], 1e-10f);
    uint4 ma[4], mb[4];
    float rsc[4], p0r[4];
    #pragma unroll
    for (int rr = 0; rr < 4; ++rr) {
        const int r = rbase + rr;
        const uint4* m4 = (const uint4*)(M + r * N + lane * 16);
        ma[rr] = m4[0]; mb[rr] = m4[1];
        rsc[rr] = (r == 0) ? 0.f : LAMB / fmaxf(total[r], 1e-10f);
        p0r[rr] = (r == 0) ? 0.f : A0[r] * r0s;
    }

    // ---- it0: z = A0 (zscale = r0s) -> zb0 ----
    {
        const float4* z4 = (const float4*)(A0 + lane * 16);
        float4 z0 = z4[0], z1 = z4[1], z2 = z4[2], z3 = z4[3];
        #pragma unroll
        for (int rr = 0; rr < 4; ++rr) {
            float acc = dotp(ma[rr], mb[rr], z0, z1, z2, z3);
            #pragma unroll
            for (int off = 32; off >= 1; off >>= 1) acc += __shfl_xor(acc, off, 64);
            if (lane == 0) st_dc_f32(&zb0[rbase + rr], p0r[rr] + rsc[rr] * r0s * acc);
        }
    }
    gridbar64(bar, 64);
    // ---- it1: z = zb0 -> zb1 ----
    {
        const float4* z4 = (const float4*)(zb0 + lane * 16);
        float4 z0 = z4[0], z1 = z4[1], z2 = z4[2], z3 = z4[3];
        #pragma unroll
        for (int rr = 0; rr < 4; ++rr) {
            float acc = dotp(ma[rr], mb[rr], z0, z1, z2, z3);
            #pragma unroll
            for (int off = 32; off >= 1; off >>= 1) acc += __shfl_xor(acc, off, 64);
            if (lane == 0) st_dc_f32(&zb1[rbase + rr], p0r[rr] + rsc[rr] * acc);
        }
    }
    gridbar64(bar, 128);
    // ---- it2: z = zb1 -> zb2 ----
    {
        const float4* z4 = (const float4*)(zb1 + lane * 16);
        float4 z0 = z4[0], z1 = z4[1], z2 = z4[2], z3 = z4[3];
        #pragma unroll
        for (int rr = 0; rr < 4; ++rr) {
            float acc = dotp(ma[rr], mb[rr], z0, z1, z2, z3);
            #pragma unroll
            for (int off = 32; off >= 1; off >>= 1) acc += __shfl_xor(acc, off, 64);
            if (lane == 0) st_dc_f32(&zb2[rbase + rr], p0r[rr] + rsc[rr] * acc);
        }
    }

    // last-block-done: fence-free (dc stores + vmcnt drain), 64 blocks
    asm volatile("s_waitcnt vmcnt(0)" ::: "memory");
    __syncthreads();
    if (t == 0) {
        unsigned int old = atomicAdd(donecnt, 1u);
        winner = (old == 63u) ? 1 : 0;
    }
    __syncthreads();
    if (!winner) return;

    // ---- 256-thread Aitken + softmax epilogue: zM=zb2, zM1=zb1, zM2=zb0 ----
    const float* zM  = zb2;
    const float* zM1 = zb1;
    const float* zM2 = zb0;
    float av[4], d1v[4];
    float s12 = 0.f, s22 = 0.f;
    #pragma unroll
    for (int k = 0; k < 4; ++k) {
        const int e = t + 256 * k;
        av[k] = zM[e];
        float bb = zM1[e], cc = zM2[e];
        d1v[k] = av[k] - bb;
        float d2 = bb - cc;
        s12 += d1v[k] * d2;
        s22 += d2 * d2;
    }
    #pragma unroll
    for (int off = 32; off >= 1; off >>= 1) s12 += __shfl_down(s12, off, 64);
    if (lane == 0) red4[wave] = s12;
    __syncthreads();
    if (t == 0) bvalS = red4[0] + red4[1] + red4[2] + red4[3];
    __syncthreads();
    const float dot12 = bvalS;
    __syncthreads();
    #pragma unroll
    for (int off = 32; off >= 1; off >>= 1) s22 += __shfl_down(s22, off, 64);
    if (lane == 0) red4[wave] = s22;
    __syncthreads();
    if (t == 0) bvalS = red4[0] + red4[1] + red4[2] + red4[3];
    __syncthreads();
    const float dot22 = bvalS;
    __syncthreads();

    float lam = dot12 / fmaxf(dot22, 1e-30f);
    lam = fminf(fmaxf(lam, 0.0f), 0.95f);
    const float coef = lam / (1.0f - lam);
    #pragma unroll
    for (int k = 0; k < 4; ++k) ush[t + 256 * k] = av[k] + coef * d1v[k];
    __syncthreads();

    float Pv[4];
    float ps = 0.f;
    #pragma unroll
    for (int k = 0; k < 4; ++k) {
        const int e = t + 256 * k;
        Pv[k] = (e >= 1) ? 0.1f * ush[e] : 0.f;
        ps += Pv[k];
    }
    #pragma unroll
    for (int off = 32; off >= 1; off >>= 1) ps += __shfl_down(ps, off, 64);
    if (lane == 0) red4[wave] = ps;
    __syncthreads();
    if (t == 0) bvalS = (red4[0] + red4[1] + red4[2] + red4[3]) / 1023.0f;
    __syncthreads();
    const float mean = bvalS;
    __syncthreads();

    float mx = 0.f;   // relu'd values >= 0
    #pragma unroll
    for (int k = 0; k < 4; ++k) {
        const int e = t + 256 * k;
        if (e >= 1) {
            Pv[k] = fmaxf(Pv[k] - mean, 0.f) * 100.f;
            mx = fmaxf(mx, Pv[k]);
        }
    }
    #pragma unroll
    for (int off = 32; off >= 1; off >>= 1) mx = fmaxf(mx, __shfl_down(mx, off, 64));
    if (lane == 0) red4[wave] = mx;
    __syncthreads();
    if (t == 0) bvalS = fmaxf(fmaxf(red4[0], red4[1]), fmaxf(red4[2], red4[3]));
    __syncthreads();
    const float gmax = bvalS;
    __syncthreads();

    float Ev[4];
    float es = 0.f;
    #pragma unroll
    for (int k = 0; k < 4; ++k) {
        const int e = t + 256 * k;
        Ev[k] = (e >= 1) ? expf(Pv[k] - gmax) : 0.f;
        es += Ev[k];
    }
    #pragma unroll
    for (int off = 32; off >= 1; off >>= 1) es += __shfl_down(es, off, 64);
    if (lane == 0) red4[wave] = es;
    __syncthreads();
    if (t == 0) bvalS = red4[0] + red4[1] + red4[2] + red4[3];
    __syncthreads();
    const float esum = bvalS;
    #pragma unroll
    for (int k = 0; k < 4; ++k) {
        const int e = t + 256 * k;
        if (e >= 1) out[e - 1] = Ev[k] / esum;
    }
}

extern "C" void kernel_launch(void* const* d_in, const int* in_sizes, int n_in,
                              void* d_out, int out_size, void* d_ws, size_t ws_size,
                              hipStream_t stream) {
    const float* f  = (const float*)d_in[0];
    const float* w1 = (const float*)d_in[1];
    const float* b1 = (const float*)d_in[2];
    const float* w2 = (const float*)d_in[3];
    const float* b2 = (const float*)d_in[4];
    const float* w3 = (const float*)d_in[5];
    const float* b3 = (const float*)d_in[6];
    const float* w4 = (const float*)d_in[7];
    const float* b4 = (const float*)d_in[8];
    float* ws = (float*)d_ws;

    // float-unit offsets
    float* fn2   = ws + 33024;                           // 1024
    float* mag   = ws + 34048;                           // 1024
    float* total = ws + 35072;                           // 1024 (zeroed in k_mlp)
    unsigned int* bar     = (unsigned int*)(ws + 36096); // memset-zeroed
    unsigned int* donecnt = (unsigned int*)(ws + 36097); // memset-zeroed
    float* A0    = ws + 36352;                           // 1024
    float* zb0   = ws + 37376;                           // 1024
    float* zb1   = ws + 38400;                           // 1024
    float* zb2   = ws + 39424;                           // 1024
    unsigned short* xb = (unsigned short*)(ws + 40448);  // 1024x128 bf16
    unsigned short* Bu = (unsigned short*)(ws + 105984); // 1024x1024 bf16
    float* out = (float*)d_out;

    // bar + donecnt (monotonic counters) cannot self-zero across graph replays.
    (void)hipMemsetAsync((char*)d_ws + 36096 * 4, 0, 8, stream);

    k_mlp<<<64, 1024, 0, stream>>>(f, w1, b1, w2, b2, w3, b3, w4, b4,
                                   xb, fn2, mag, total);
    k_aff<<<256, 256, 0, stream>>>(xb, mag, fn2, Bu, A0, total);
    k_mv3<<<64, 256, 0, stream>>>(Bu, A0, total, zb0, zb1, zb2,
                                  bar, donecnt, out);
}